// Round 1
// baseline (2670.041 us; speedup 1.0000x reference)
//
#include <hip/hip_runtime.h>
#include <cstdint>
#include <cstddef>

#define NN 25000        // nodes
#define NE 100000       // edges
#define NEP 125000      // edges + self loops
#define NG 512          // graphs
#define HEADS 10
#define FXD 78
#define HF 780          // HEADS*FXD
#define SEQ 1000
#define EMBD 128
#define NFILT 32
#define VOCAB 26
#define CONVO 121       // EMB-8+1
#define KCONV 8
#define VK (VOCAB*KCONV)     // 208
#define AROW (NFILT*VK)      // 6656

// ---------------------------------------------------------------- CSR build
__global__ void k_deg(const int* __restrict__ ei, int* __restrict__ deg) {
    int e = blockIdx.x * blockDim.x + threadIdx.x;
    if (e >= NEP) return;
    int d = (e < NE) ? ei[NE + e] : (e - NE);
    atomicAdd(&deg[d], 1);
}

__global__ void k_scan(const int* __restrict__ deg, int* __restrict__ off) {
    __shared__ int buf[1024];
    __shared__ int carry;
    int tid = threadIdx.x;
    if (tid == 0) carry = 0;
    __syncthreads();
    for (int base = 0; base < NN; base += 1024) {
        int i = base + tid;
        int v = (i < NN) ? deg[i] : 0;
        buf[tid] = v;
        __syncthreads();
        for (int o = 1; o < 1024; o <<= 1) {
            int t = (tid >= o) ? buf[tid - o] : 0;
            __syncthreads();
            buf[tid] += t;
            __syncthreads();
        }
        if (i < NN) off[i] = carry + buf[tid] - v;   // exclusive
        int tot = buf[1023];
        __syncthreads();
        if (tid == 0) carry += tot;
        __syncthreads();
    }
    if (tid == 0) off[NN] = carry;
}

__global__ void k_fill(const int* __restrict__ ei, const int* __restrict__ off,
                       int* __restrict__ fill, int* __restrict__ csrc, int* __restrict__ cdst) {
    int e = blockIdx.x * blockDim.x + threadIdx.x;
    if (e >= NEP) return;
    int s = (e < NE) ? ei[e]      : (e - NE);
    int d = (e < NE) ? ei[NE + e] : (e - NE);
    int pos = off[d] + atomicAdd(&fill[d], 1);
    csrc[pos] = s;
    cdst[pos] = d;
}

__global__ void k_dinv(const int* __restrict__ deg, float* __restrict__ dinv) {
    int n = blockIdx.x * blockDim.x + threadIdx.x;
    if (n >= NN) return;
    int dg = deg[n];
    dinv[n] = dg > 0 ? 1.0f / sqrtf((float)dg) : 0.0f;
}

// ---------------------------------------------------------------- GAT attention
// per-wave: one node; both dot products in one pass over the h row
__global__ void k_att(const float* __restrict__ h, const float* __restrict__ wsrc,
                      const float* __restrict__ wdst, float* __restrict__ asrc,
                      float* __restrict__ adst) {
    int node = blockIdx.x * 4 + (threadIdx.x >> 6);
    int lane = threadIdx.x & 63;
    if (node >= NN) return;
    const float* row = h + (size_t)node * HF;
    for (int hh = 0; hh < HEADS; ++hh) {
        float ps = 0.f, pd = 0.f;
        for (int f = lane; f < FXD; f += 64) {
            float v = row[hh * FXD + f];
            ps += v * wsrc[hh * FXD + f];
            pd += v * wdst[hh * FXD + f];
        }
        for (int o = 32; o > 0; o >>= 1) {
            ps += __shfl_down(ps, o);
            pd += __shfl_down(pd, o);
        }
        if (lane == 0) {
            asrc[node * HEADS + hh] = ps;
            adst[node * HEADS + hh] = pd;
        }
    }
}

// per (dst,head): segment max + exp-sum
__global__ void k_mden(const int* __restrict__ off, const int* __restrict__ csrc,
                       const float* __restrict__ asrc, const float* __restrict__ adst,
                       float* __restrict__ mbuf, float* __restrict__ dbuf) {
    int idx = blockIdx.x * blockDim.x + threadIdx.x;
    if (idx >= NN * HEADS) return;
    int d = idx / HEADS, hh = idx % HEADS;
    int s0 = off[d], s1 = off[d + 1];
    float ad = adst[idx];
    float m = -1e30f;
    for (int p = s0; p < s1; ++p) {
        float v = asrc[csrc[p] * HEADS + hh] + ad;
        v = v > 0.f ? v : 0.2f * v;
        m = fmaxf(m, v);
    }
    float den = 0.f;
    for (int p = s0; p < s1; ++p) {
        float v = asrc[csrc[p] * HEADS + hh] + ad;
        v = v > 0.f ? v : 0.2f * v;
        den += expf(v - m);
    }
    mbuf[idx] = m;
    dbuf[idx] = den;
}

__global__ void k_alpha(const int* __restrict__ csrc, const int* __restrict__ cdst,
                        const float* __restrict__ asrc, const float* __restrict__ adst,
                        const float* __restrict__ mbuf, const float* __restrict__ dbuf,
                        float* __restrict__ alpha) {
    int p = blockIdx.x * blockDim.x + threadIdx.x;
    if (p >= NEP) return;
    int s = csrc[p], d = cdst[p];
#pragma unroll
    for (int hh = 0; hh < HEADS; ++hh) {
        float v = asrc[s * HEADS + hh] + adst[d * HEADS + hh];
        v = v > 0.f ? v : 0.2f * v;
        alpha[(size_t)p * HEADS + hh] =
            expf(v - mbuf[d * HEADS + hh]) / (dbuf[d * HEADS + hh] + 1e-16f);
    }
}

// block per dst node: x1[d,f] = relu( sum_e alpha[e, f/78] * h[src_e, f] + gat_b[f] )
__global__ __launch_bounds__(256) void k_gat_feat(
    const int* __restrict__ off, const int* __restrict__ csrc,
    const float* __restrict__ alpha, const float* __restrict__ h,
    const float* __restrict__ gat_b, float* __restrict__ x1) {
    __shared__ float lal[64 * HEADS];
    __shared__ int lsrc[64];
    int d = blockIdx.x, tid = threadIdx.x;
    int s0 = off[d], s1 = off[d + 1];
    float acc[4] = {0.f, 0.f, 0.f, 0.f};
    int hh[4];
#pragma unroll
    for (int t = 0; t < 4; ++t) { int f = tid + t * 256; hh[t] = (f < HF) ? f / FXD : 0; }
    for (int c0 = s0; c0 < s1; c0 += 64) {
        int cs = min(64, s1 - c0);
        __syncthreads();
        for (int i = tid; i < cs * HEADS; i += 256) lal[i] = alpha[(size_t)c0 * HEADS + i];
        for (int i = tid; i < cs; i += 256) lsrc[i] = csrc[c0 + i];
        __syncthreads();
        for (int e = 0; e < cs; ++e) {
            const float* hrow = h + (size_t)lsrc[e] * HF;
#pragma unroll
            for (int t = 0; t < 4; ++t) {
                int f = tid + t * 256;
                if (f < HF) acc[t] += lal[e * HEADS + hh[t]] * hrow[f];
            }
        }
    }
#pragma unroll
    for (int t = 0; t < 4; ++t) {
        int f = tid + t * 256;
        if (f < HF) x1[(size_t)d * HF + f] = fmaxf(acc[t] + gat_b[f], 0.f);
    }
}

// block per dst node: y[d,f] = sum_e dinv[s]*dinv[d] * x1[s,f]   (GCN agg BEFORE the GEMM)
__global__ __launch_bounds__(256) void k_gcn_agg(
    const int* __restrict__ off, const int* __restrict__ csrc,
    const float* __restrict__ dinv, const float* __restrict__ x1,
    float* __restrict__ y) {
    __shared__ float lno[256];
    __shared__ int lsrc[256];
    int d = blockIdx.x, tid = threadIdx.x;
    int s0 = off[d], s1 = off[d + 1];
    float dd = dinv[d];
    float acc[4] = {0.f, 0.f, 0.f, 0.f};
    for (int c0 = s0; c0 < s1; c0 += 256) {
        int cs = min(256, s1 - c0);
        __syncthreads();
        for (int i = tid; i < cs; i += 256) {
            int s = csrc[c0 + i];
            lsrc[i] = s;
            lno[i] = dinv[s] * dd;
        }
        __syncthreads();
        for (int e = 0; e < cs; ++e) {
            const float* row = x1 + (size_t)lsrc[e] * HF;
            float w = lno[e];
#pragma unroll
            for (int t = 0; t < 4; ++t) {
                int f = tid + t * 256;
                if (f < HF) acc[t] += w * row[f];
            }
        }
    }
#pragma unroll
    for (int t = 0; t < 4; ++t) {
        int f = tid + t * 256;
        if (f < HF) y[(size_t)d * HF + f] = acc[t];
    }
}

// ---------------------------------------------------------------- pooling
__global__ void k_gstart(const int* __restrict__ batch, int* __restrict__ gstart) {
    int g = blockIdx.x * blockDim.x + threadIdx.x;
    if (g > NG) return;
    int lo = 0, hi = NN;
    while (lo < hi) {
        int mid = (lo + hi) >> 1;
        if (batch[mid] < g) lo = mid + 1; else hi = mid;
    }
    gstart[g] = lo;
}

__global__ __launch_bounds__(256) void k_pool(const int* __restrict__ gstart,
                                              const float* __restrict__ x2,
                                              float* __restrict__ pool) {
    int g = blockIdx.x, tid = threadIdx.x;
    int s0 = gstart[g], s1 = gstart[g + 1];
    float mx[4] = {0.f, 0.f, 0.f, 0.f};
    float sm[4] = {0.f, 0.f, 0.f, 0.f};
    for (int n = s0; n < s1; ++n) {
        const float* row = x2 + (size_t)n * HF;
#pragma unroll
        for (int t = 0; t < 4; ++t) {
            int f = tid + t * 256;
            if (f < HF) { float v = row[f]; sm[t] += v; mx[t] = fmaxf(mx[t], v); }
        }
    }
    float inv = 1.0f / (float)max(s1 - s0, 1);
#pragma unroll
    for (int t = 0; t < 4; ++t) {
        int f = tid + t * 256;
        if (f < HF) {
            pool[(size_t)g * (2 * HF) + f] = mx[t];              // g_max first
            pool[(size_t)g * (2 * HF) + HF + f] = sm[t] * inv;   // then g_mean
        }
    }
}

// ---------------------------------------------------------------- dense GEMMs
// C[M,N] = act(A[M,K] @ B[K,N] + bias), C row stride ldc. 128x128 tile, 8x8 micro.
__global__ __launch_bounds__(256) void k_gemm128(
    const float* __restrict__ A, const float* __restrict__ B,
    const float* __restrict__ bias, float* __restrict__ C,
    int M, int N, int K, int ldc, int relu) {
    __shared__ __align__(16) float As[8][132];
    __shared__ __align__(16) float Bs[8][132];
    int bm = blockIdx.x * 128, bn = blockIdx.y * 128;
    int tid = threadIdx.x;
    int tx = tid & 15, ty = tid >> 4;
    float acc[8][8] = {};
    for (int k0 = 0; k0 < K; k0 += 8) {
        __syncthreads();
#pragma unroll
        for (int t = 0; t < 4; ++t) {
            int e = tid + t * 256;
            int r = e >> 3, kk = e & 7;
            int gr = bm + r, gk = k0 + kk;
            As[kk][r] = (gr < M && gk < K) ? A[(size_t)gr * K + gk] : 0.f;
        }
#pragma unroll
        for (int t = 0; t < 4; ++t) {
            int e = tid + t * 256;
            int kk = e >> 7, c = e & 127;
            int gc = bn + c, gk = k0 + kk;
            Bs[kk][c] = (gc < N && gk < K) ? B[(size_t)gk * N + gc] : 0.f;
        }
        __syncthreads();
#pragma unroll
        for (int kk = 0; kk < 8; ++kk) {
            float4 a0 = *reinterpret_cast<const float4*>(&As[kk][ty * 8]);
            float4 a1 = *reinterpret_cast<const float4*>(&As[kk][ty * 8 + 4]);
            float4 b0 = *reinterpret_cast<const float4*>(&Bs[kk][tx * 8]);
            float4 b1 = *reinterpret_cast<const float4*>(&Bs[kk][tx * 8 + 4]);
            float av[8] = {a0.x, a0.y, a0.z, a0.w, a1.x, a1.y, a1.z, a1.w};
            float bv[8] = {b0.x, b0.y, b0.z, b0.w, b1.x, b1.y, b1.z, b1.w};
#pragma unroll
            for (int i = 0; i < 8; ++i)
#pragma unroll
                for (int j = 0; j < 8; ++j) acc[i][j] += av[i] * bv[j];
        }
    }
#pragma unroll
    for (int i = 0; i < 8; ++i) {
        int row = bm + ty * 8 + i;
        if (row >= M) break;
#pragma unroll
        for (int j = 0; j < 8; ++j) {
            int col = bn + tx * 8 + j;
            if (col >= N) break;
            float v = acc[i][j];
            if (bias) v += bias[col];
            if (relu) v = fmaxf(v, 0.f);
            C[(size_t)row * ldc + col] = v;
        }
    }
}

// 64x64 tile, 4x4 micro — for the skinny M=512 GEMMs (more blocks)
__global__ __launch_bounds__(256) void k_gemm64(
    const float* __restrict__ A, const float* __restrict__ B,
    const float* __restrict__ bias, float* __restrict__ C,
    int M, int N, int K, int ldc, int relu) {
    __shared__ __align__(16) float As[16][68];
    __shared__ __align__(16) float Bs[16][68];
    int bm = blockIdx.x * 64, bn = blockIdx.y * 64;
    int tid = threadIdx.x;
    int tx = tid & 15, ty = tid >> 4;
    float acc[4][4] = {};
    for (int k0 = 0; k0 < K; k0 += 16) {
        __syncthreads();
#pragma unroll
        for (int t = 0; t < 4; ++t) {
            int e = tid + t * 256;
            int r = e >> 4, kk = e & 15;
            int gr = bm + r, gk = k0 + kk;
            As[kk][r] = (gr < M && gk < K) ? A[(size_t)gr * K + gk] : 0.f;
        }
#pragma unroll
        for (int t = 0; t < 4; ++t) {
            int e = tid + t * 256;
            int kk = e >> 6, c = e & 63;
            int gc = bn + c, gk = k0 + kk;
            Bs[kk][c] = (gc < N && gk < K) ? B[(size_t)gk * N + gc] : 0.f;
        }
        __syncthreads();
#pragma unroll
        for (int kk = 0; kk < 16; ++kk) {
            float4 a = *reinterpret_cast<const float4*>(&As[kk][ty * 4]);
            float4 b = *reinterpret_cast<const float4*>(&Bs[kk][tx * 4]);
            float av[4] = {a.x, a.y, a.z, a.w};
            float bv[4] = {b.x, b.y, b.z, b.w};
#pragma unroll
            for (int i = 0; i < 4; ++i)
#pragma unroll
                for (int j = 0; j < 4; ++j) acc[i][j] += av[i] * bv[j];
        }
    }
#pragma unroll
    for (int i = 0; i < 4; ++i) {
        int row = bm + ty * 4 + i;
        if (row >= M) break;
#pragma unroll
        for (int j = 0; j < 4; ++j) {
            int col = bn + tx * 4 + j;
            if (col >= N) break;
            float v = acc[i][j];
            if (bias) v += bias[col];
            if (relu) v = fmaxf(v, 0.f);
            C[(size_t)row * ldc + col] = v;
        }
    }
}

// ---------------------------------------------------------------- conv branch
// B[(v*8+k), p] = emb[v, p+k]
__global__ void k_bmat(const float* __restrict__ emb, float* __restrict__ Bm) {
    int b = blockIdx.x;          // 0..207
    int p = threadIdx.x;
    if (p >= CONVO) return;
    int v = b >> 3, k = b & 7;
    Bm[b * CONVO + p] = emb[v * EMBD + p + k];
}

// A[g][o][v][k] = sum_{s: target[g,s]==v} conv_W[o,s,k]
__global__ __launch_bounds__(256) void k_Amat(const int* __restrict__ target,
                                              const float* __restrict__ convW,
                                              float* __restrict__ Am) {
    __shared__ float acc[AROW];  // 32*208 = 6656 floats
    int g = blockIdx.x, tid = threadIdx.x;
    for (int i = tid; i < AROW; i += 256) acc[i] = 0.f;
    __syncthreads();
    int o = tid >> 3, k = tid & 7;   // 256 threads = 32*8 exactly
    const int* tg = target + (size_t)g * SEQ;
    for (int s = 0; s < SEQ; ++s) {
        int v = tg[s];
        acc[o * VK + v * KCONV + k] += convW[o * (SEQ * KCONV) + s * KCONV + k];
    }
    __syncthreads();
    for (int i = tid; i < AROW; i += 256) Am[(size_t)g * AROW + i] = acc[i];
}

// conv[g,o,p] = sum_vk A[g,o,vk] * B[vk,p] + conv_b[o]
__global__ __launch_bounds__(128) void k_conv(const float* __restrict__ Am,
                                              const float* __restrict__ Bm,
                                              const float* __restrict__ convb,
                                              float* __restrict__ out) {
    __shared__ float As[AROW];
    int g = blockIdx.x, tid = threadIdx.x;
    for (int i = tid; i < AROW; i += 128) As[i] = Am[(size_t)g * AROW + i];
    __syncthreads();
    if (tid >= CONVO) return;
    int p = tid;
    float acc[NFILT] = {};
    for (int vk = 0; vk < VK; ++vk) {
        float b = Bm[vk * CONVO + p];
#pragma unroll
        for (int o = 0; o < NFILT; ++o) acc[o] += As[o * VK + vk] * b;
    }
#pragma unroll
    for (int o = 0; o < NFILT; ++o)
        out[(size_t)g * (NFILT * CONVO) + o * CONVO + p] = acc[o] + convb[o];
}

// ---------------------------------------------------------------- launch
extern "C" void kernel_launch(void* const* d_in, const int* in_sizes, int n_in,
                              void* d_out, int out_size, void* d_ws, size_t ws_size,
                              hipStream_t stream) {
    const float* x        = (const float*)d_in[0];
    const int*   ei       = (const int*)d_in[1];
    const int*   batch    = (const int*)d_in[2];
    const int*   target   = (const int*)d_in[3];
    const float* gat_W    = (const float*)d_in[4];
    const float* gat_as   = (const float*)d_in[5];
    const float* gat_ad   = (const float*)d_in[6];
    const float* gat_b    = (const float*)d_in[7];
    const float* gcn_W    = (const float*)d_in[8];
    const float* gcn_b    = (const float*)d_in[9];
    const float* fcg1_W   = (const float*)d_in[10];
    const float* fcg1_b   = (const float*)d_in[11];
    const float* fcg2_W   = (const float*)d_in[12];
    const float* fcg2_b   = (const float*)d_in[13];
    const float* emb      = (const float*)d_in[14];
    const float* conv_W   = (const float*)d_in[15];
    const float* conv_b   = (const float*)d_in[16];
    const float* fcxt_W   = (const float*)d_in[17];
    const float* fcxt_b   = (const float*)d_in[18];
    const float* fc1_W    = (const float*)d_in[19];
    const float* fc1_b    = (const float*)d_in[20];
    const float* fc2_W    = (const float*)d_in[21];
    const float* fc2_b    = (const float*)d_in[22];
    const float* out_W    = (const float*)d_in[23];
    const float* out_b    = (const float*)d_in[24];
    float* outp = (float*)d_out;

    // ---- workspace layout (bigA/bigB ping-pong the two 78MB node matrices) ----
    const size_t BIG = (size_t)NN * HF;
    float* bigA   = (float*)d_ws;                 // h, then y, then small-buffer arena
    float* bigB   = bigA + BIG;                   // x1, then x2
    float* asrc   = bigB + BIG;
    float* adst   = asrc + (size_t)NN * HEADS;
    float* mbuf   = adst + (size_t)NN * HEADS;
    float* dbuf   = mbuf + (size_t)NN * HEADS;
    float* alpha  = dbuf + (size_t)NN * HEADS;
    float* dinv   = alpha + (size_t)NEP * HEADS;
    int* deg      = (int*)(dinv + NN);
    int* csr_off  = deg + NN;
    int* csr_fill = csr_off + (NN + 1);
    int* csr_src  = csr_fill + NN;
    int* csr_dst  = csr_src + NEP;
    int* gstart   = csr_dst + NEP;
    // small arena aliased into bigA (free once x2 is computed)
    float* pool    = bigA;                                  // 512*1560
    float* xg1     = pool + (size_t)NG * 2 * HF;            // 512*1024
    float* xc      = xg1 + (size_t)NG * 1024;               // 512*256
    float* f1      = xc + (size_t)NG * 256;                 // 512*1024
    float* f2      = f1 + (size_t)NG * 1024;                // 512*512
    float* Amat    = f2 + (size_t)NG * 512;                 // 512*6656
    float* Bmat    = Amat + (size_t)NG * AROW;              // 208*121
    float* convout = Bmat + (size_t)VK * CONVO;             // 512*3872

    hipMemsetAsync(deg, 0, NN * sizeof(int), stream);
    hipMemsetAsync(csr_fill, 0, NN * sizeof(int), stream);

    // ---- GAT ----
    k_gemm128<<<dim3((NN + 127) / 128, (HF + 127) / 128), 256, 0, stream>>>(
        x, gat_W, nullptr, bigA, NN, HF, FXD, HF, 0);                   // h = x@gat_W
    k_att<<<(NN + 3) / 4, 256, 0, stream>>>(bigA, gat_as, gat_ad, asrc, adst);
    k_deg<<<(NEP + 255) / 256, 256, 0, stream>>>(ei, deg);
    k_scan<<<1, 1024, 0, stream>>>(deg, csr_off);
    k_fill<<<(NEP + 255) / 256, 256, 0, stream>>>(ei, csr_off, csr_fill, csr_src, csr_dst);
    k_dinv<<<(NN + 255) / 256, 256, 0, stream>>>(deg, dinv);
    k_mden<<<(NN * HEADS + 255) / 256, 256, 0, stream>>>(csr_off, csr_src, asrc, adst, mbuf, dbuf);
    k_alpha<<<(NEP + 255) / 256, 256, 0, stream>>>(csr_src, csr_dst, asrc, adst, mbuf, dbuf, alpha);
    k_gat_feat<<<NN, 256, 0, stream>>>(csr_off, csr_src, alpha, bigA, gat_b, bigB); // x1

    // ---- GCN (aggregate first, then one dense GEMM) ----
    k_gcn_agg<<<NN, 256, 0, stream>>>(csr_off, csr_src, dinv, bigB, bigA);          // y
    k_gemm128<<<dim3((NN + 127) / 128, (HF + 127) / 128), 256, 0, stream>>>(
        bigA, gcn_W, gcn_b, bigB, NN, HF, HF, HF, 1);                   // x2 = relu(y@W+b)

    // ---- pooling + graph MLP ----
    k_gstart<<<1, 1024, 0, stream>>>(batch, gstart);
    k_pool<<<NG, 256, 0, stream>>>(gstart, bigB, pool);
    k_gemm64<<<dim3(8, 16), 256, 0, stream>>>(pool, fcg1_W, fcg1_b, xg1, NG, 1024, 2 * HF, 1024, 1);
    k_gemm64<<<dim3(8, 2), 256, 0, stream>>>(xg1, fcg2_W, fcg2_b, xc, NG, 128, 1024, 256, 0);

    // ---- target CNN branch (vocab-factorized conv) ----
    k_bmat<<<VK, 128, 0, stream>>>(emb, Bmat);
    k_Amat<<<NG, 256, 0, stream>>>(target, conv_W, Amat);
    k_conv<<<NG, 128, 0, stream>>>(Amat, Bmat, conv_b, convout);
    k_gemm64<<<dim3(8, 2), 256, 0, stream>>>(convout, fcxt_W, fcxt_b, xc + 128, NG, 128,
                                             NFILT * CONVO, 256, 0);

    // ---- fusion head ----
    k_gemm64<<<dim3(8, 16), 256, 0, stream>>>(xc, fc1_W, fc1_b, f1, NG, 1024, 256, 1024, 1);
    k_gemm64<<<dim3(8, 8), 256, 0, stream>>>(f1, fc2_W, fc2_b, f2, NG, 512, 1024, 512, 1);
    k_gemm64<<<dim3(8, 1), 256, 0, stream>>>(f2, out_W, out_b, outp, NG, 1, 512, 1, 0);
}

// Round 2
// 1922.906 us; speedup vs baseline: 1.3885x; 1.3885x over previous
//
#include <hip/hip_runtime.h>
#include <cstdint>
#include <cstddef>

#define NN 25000        // nodes
#define NE 100000       // edges
#define NEP 125000      // edges + self loops
#define NG 512          // graphs
#define HEADS 10
#define FXD 78
#define KPAD 80         // padded K for GAT gemm (float4-aligned)
#define HF 780          // HEADS*FXD
#define SEQ 1000
#define EMBD 128
#define NFILT 32
#define VOCAB 26
#define CONVO 121       // EMB-8+1
#define KCONV 8
#define VK (VOCAB*KCONV)     // 208
#define AROW (NFILT*VK)      // 6656

// ---------------------------------------------------------------- CSR build
__global__ void k_deg(const int* __restrict__ ei, int* __restrict__ deg) {
    int e = blockIdx.x * blockDim.x + threadIdx.x;
    if (e >= NEP) return;
    int d = (e < NE) ? ei[NE + e] : (e - NE);
    atomicAdd(&deg[d], 1);
}

// 1 block, 1024 threads, 25 elems/thread serial + one LDS scan (20 barriers total)
__global__ __launch_bounds__(1024) void k_scan(const int* __restrict__ deg, int* __restrict__ off) {
    __shared__ int tsum[1024];
    const int tid = threadIdx.x;
    const int base = tid * 25;
    int s = 0;
    for (int i = 0; i < 25; ++i) { int g = base + i; if (g < NN) s += deg[g]; }
    tsum[tid] = s;
    __syncthreads();
    for (int o = 1; o < 1024; o <<= 1) {
        int v = (tid >= o) ? tsum[tid - o] : 0;
        __syncthreads();
        tsum[tid] += v;
        __syncthreads();
    }
    int run = tid ? tsum[tid - 1] : 0;   // exclusive prefix of this chunk
    for (int i = 0; i < 25; ++i) {
        int g = base + i;
        if (g < NN) { off[g] = run; run += deg[g]; }
    }
    if (tid == 1023) off[NN] = tsum[1023];
}

__global__ void k_fill(const int* __restrict__ ei, const int* __restrict__ off,
                       int* __restrict__ fill, int* __restrict__ csrc) {
    int e = blockIdx.x * blockDim.x + threadIdx.x;
    if (e >= NEP) return;
    int s = (e < NE) ? ei[e]      : (e - NE);
    int d = (e < NE) ? ei[NE + e] : (e - NE);
    int pos = off[d] + atomicAdd(&fill[d], 1);
    csrc[pos] = s;
}

__global__ void k_dinv(const int* __restrict__ deg, float* __restrict__ dinv) {
    int n = blockIdx.x * blockDim.x + threadIdx.x;
    if (n >= NN) return;
    int dg = deg[n];
    dinv[n] = dg > 0 ? 1.0f / sqrtf((float)dg) : 0.0f;
}

// ---------------------------------------------------------------- GAT attention
__global__ void k_att(const float* __restrict__ h, const float* __restrict__ wsrc,
                      const float* __restrict__ wdst, float* __restrict__ asrc,
                      float* __restrict__ adst) {
    int node = blockIdx.x * 4 + (threadIdx.x >> 6);
    int lane = threadIdx.x & 63;
    if (node >= NN) return;
    const float* row = h + (size_t)node * HF;
    for (int hh = 0; hh < HEADS; ++hh) {
        float ps = 0.f, pd = 0.f;
        for (int f = lane; f < FXD; f += 64) {
            float v = row[hh * FXD + f];
            ps += v * wsrc[hh * FXD + f];
            pd += v * wdst[hh * FXD + f];
        }
        for (int o = 32; o > 0; o >>= 1) {
            ps += __shfl_down(ps, o);
            pd += __shfl_down(pd, o);
        }
        if (lane == 0) {
            asrc[node * HEADS + hh] = ps;
            adst[node * HEADS + hh] = pd;
        }
    }
}

// per (dst,head): segment max + exp-sum
__global__ void k_mden(const int* __restrict__ off, const int* __restrict__ csrc,
                       const float* __restrict__ asrc, const float* __restrict__ adst,
                       float* __restrict__ mbuf, float* __restrict__ dbuf) {
    int idx = blockIdx.x * blockDim.x + threadIdx.x;
    if (idx >= NN * HEADS) return;
    int d = idx / HEADS, hh = idx % HEADS;
    int s0 = off[d], s1 = off[d + 1];
    float ad = adst[idx];
    float m = -1e30f;
    for (int p = s0; p < s1; ++p) {
        float v = asrc[csrc[p] * HEADS + hh] + ad;
        v = v > 0.f ? v : 0.2f * v;
        m = fmaxf(m, v);
    }
    float den = 0.f;
    for (int p = s0; p < s1; ++p) {
        float v = asrc[csrc[p] * HEADS + hh] + ad;
        v = v > 0.f ? v : 0.2f * v;
        den += expf(v - m);
    }
    mbuf[idx] = m;
    dbuf[idx] = den;
}

// block per dst node: alpha computed inline (fused), float4 feature MACs
__global__ __launch_bounds__(256) void k_gat_feat(
    const int* __restrict__ off, const int* __restrict__ csrc,
    const float* __restrict__ asrc, const float* __restrict__ adst,
    const float* __restrict__ mbuf, const float* __restrict__ dbuf,
    const float* __restrict__ h, const float* __restrict__ gat_b,
    float* __restrict__ x1) {
    __shared__ float lal[64 * HEADS];
    __shared__ int lsrc[64];
    __shared__ float s_ad[HEADS], s_m[HEADS], s_rd[HEADS];
    const int d = blockIdx.x, tid = threadIdx.x;
    if (tid < HEADS) {
        s_ad[tid] = adst[d * HEADS + tid];
        s_m[tid]  = mbuf[d * HEADS + tid];
        s_rd[tid] = 1.0f / (dbuf[d * HEADS + tid] + 1e-16f);
    }
    const int s0 = off[d], s1 = off[d + 1];
    int hj[4];
#pragma unroll
    for (int j = 0; j < 4; ++j) hj[j] = (tid < 195) ? (tid * 4 + j) / FXD : 0;
    float4 acc = {0.f, 0.f, 0.f, 0.f};
    for (int c0 = s0; c0 < s1; c0 += 64) {
        int cs = min(64, s1 - c0);
        __syncthreads();
        for (int i = tid; i < cs; i += 256) lsrc[i] = csrc[c0 + i];
        __syncthreads();
        for (int i = tid; i < cs * HEADS; i += 256) {
            int e = i / HEADS, hh = i - e * HEADS;
            float v = asrc[lsrc[e] * HEADS + hh] + s_ad[hh];
            v = v > 0.f ? v : 0.2f * v;
            lal[i] = __expf(v - s_m[hh]) * s_rd[hh];
        }
        __syncthreads();
        if (tid < 195) {
            for (int e = 0; e < cs; ++e) {
                const float4 hv = reinterpret_cast<const float4*>(h + (size_t)lsrc[e] * HF)[tid];
                const float* w = &lal[e * HEADS];
                acc.x += w[hj[0]] * hv.x;
                acc.y += w[hj[1]] * hv.y;
                acc.z += w[hj[2]] * hv.z;
                acc.w += w[hj[3]] * hv.w;
            }
        }
    }
    if (tid < 195) {
        float4 b = reinterpret_cast<const float4*>(gat_b)[tid];
        float4 o;
        o.x = fmaxf(acc.x + b.x, 0.f);
        o.y = fmaxf(acc.y + b.y, 0.f);
        o.z = fmaxf(acc.z + b.z, 0.f);
        o.w = fmaxf(acc.w + b.w, 0.f);
        reinterpret_cast<float4*>(x1 + (size_t)d * HF)[tid] = o;
    }
}

// block per dst node: y[d,:] = sum_e dinv[s]*dinv[d]*x1[s,:]   (float4)
__global__ __launch_bounds__(256) void k_gcn_agg(
    const int* __restrict__ off, const int* __restrict__ csrc,
    const float* __restrict__ dinv, const float* __restrict__ x1,
    float* __restrict__ y) {
    __shared__ float lno[256];
    __shared__ int lsrc[256];
    const int d = blockIdx.x, tid = threadIdx.x;
    const int s0 = off[d], s1 = off[d + 1];
    const float dd = dinv[d];
    float4 acc = {0.f, 0.f, 0.f, 0.f};
    for (int c0 = s0; c0 < s1; c0 += 256) {
        int cs = min(256, s1 - c0);
        __syncthreads();
        for (int i = tid; i < cs; i += 256) {
            int s = csrc[c0 + i];
            lsrc[i] = s;
            lno[i] = dinv[s] * dd;
        }
        __syncthreads();
        if (tid < 195) {
            for (int e = 0; e < cs; ++e) {
                const float4 v = reinterpret_cast<const float4*>(x1 + (size_t)lsrc[e] * HF)[tid];
                float w = lno[e];
                acc.x += w * v.x; acc.y += w * v.y; acc.z += w * v.z; acc.w += w * v.w;
            }
        }
    }
    if (tid < 195) reinterpret_cast<float4*>(y + (size_t)d * HF)[tid] = acc;
}

// ---------------------------------------------------------------- pooling
__global__ void k_gstart(const int* __restrict__ batch, int* __restrict__ gstart) {
    int g = blockIdx.x * blockDim.x + threadIdx.x;
    if (g > NG) return;
    int lo = 0, hi = NN;
    while (lo < hi) {
        int mid = (lo + hi) >> 1;
        if (batch[mid] < g) lo = mid + 1; else hi = mid;
    }
    gstart[g] = lo;
}

__global__ __launch_bounds__(256) void k_pool(const int* __restrict__ gstart,
                                              const float* __restrict__ x2,
                                              float* __restrict__ pool) {
    const int g = blockIdx.x, tid = threadIdx.x;
    const int s0 = gstart[g], s1 = gstart[g + 1];
    if (tid >= 195) return;
    float4 mx = {0.f, 0.f, 0.f, 0.f};
    float4 sm = {0.f, 0.f, 0.f, 0.f};
    for (int n = s0; n < s1; ++n) {
        float4 v = reinterpret_cast<const float4*>(x2 + (size_t)n * HF)[tid];
        sm.x += v.x; sm.y += v.y; sm.z += v.z; sm.w += v.w;
        mx.x = fmaxf(mx.x, v.x); mx.y = fmaxf(mx.y, v.y);
        mx.z = fmaxf(mx.z, v.z); mx.w = fmaxf(mx.w, v.w);
    }
    float inv = 1.0f / (float)max(s1 - s0, 1);
    sm.x *= inv; sm.y *= inv; sm.z *= inv; sm.w *= inv;
    reinterpret_cast<float4*>(pool + (size_t)g * (2 * HF))[tid] = mx;
    reinterpret_cast<float4*>(pool + (size_t)g * (2 * HF) + HF)[tid] = sm;
}

// ---------------------------------------------------------------- dense GEMMs
// 128x128 tile, BK=16, 8x8 micro in 2x2 blocks of 4 (conflict-free), reg prefetch.
// KB = valid rows of B (K may be padded past it for A).
__global__ __launch_bounds__(256) void k_gemm128(
    const float* __restrict__ A, const float* __restrict__ B,
    const float* __restrict__ bias, float* __restrict__ C,
    int M, int N, int K, int KB, int ldc, int relu) {
    __shared__ __align__(16) float As[16][128];
    __shared__ __align__(16) float Bs[16][128];
    const int bm = blockIdx.x * 128, bn = blockIdx.y * 128;
    const int tid = threadIdx.x;
    const int tx = tid & 15, ty = tid >> 4;
    const int arow0 = tid >> 2;          // +t*64
    const int akq   = (tid & 3) * 4;     // k-offset within tile
    const int bkk0  = tid >> 5;          // +t*8
    const int bc4   = (tid & 31) * 4;    // col offset within tile
    const int nt = (K + 15) / 16;
    float4 pa[2], pb[2];

    auto load_tile = [&](int k0) {
#pragma unroll
        for (int t = 0; t < 2; ++t) {
            int r = arow0 + t * 64, gr = bm + r, gk = k0 + akq;
            float4 v = {0.f, 0.f, 0.f, 0.f};
            if (gr < M && gk + 4 <= K) v = *reinterpret_cast<const float4*>(&A[(size_t)gr * K + gk]);
            pa[t] = v;
            int kk = k0 + bkk0 + t * 8, gc = bn + bc4;
            float4 w = {0.f, 0.f, 0.f, 0.f};
            if (kk < KB && gc + 4 <= N) w = *reinterpret_cast<const float4*>(&B[(size_t)kk * N + gc]);
            pb[t] = w;
        }
    };
    auto store_tile = [&]() {
#pragma unroll
        for (int t = 0; t < 2; ++t) {
            int r = arow0 + t * 64;
            As[akq + 0][r] = pa[t].x; As[akq + 1][r] = pa[t].y;
            As[akq + 2][r] = pa[t].z; As[akq + 3][r] = pa[t].w;
            *reinterpret_cast<float4*>(&Bs[bkk0 + t * 8][bc4]) = pb[t];
        }
    };

    float acc[8][8] = {};
    load_tile(0);
    store_tile();
    __syncthreads();
    for (int tile = 0; tile < nt; ++tile) {
        if (tile + 1 < nt) load_tile((tile + 1) * 16);   // prefetch overlaps compute
#pragma unroll
        for (int kk = 0; kk < 16; ++kk) {
            float4 a0 = *reinterpret_cast<const float4*>(&As[kk][ty * 4]);
            float4 a1 = *reinterpret_cast<const float4*>(&As[kk][64 + ty * 4]);
            float4 b0 = *reinterpret_cast<const float4*>(&Bs[kk][tx * 4]);
            float4 b1 = *reinterpret_cast<const float4*>(&Bs[kk][64 + tx * 4]);
            float av[8] = {a0.x, a0.y, a0.z, a0.w, a1.x, a1.y, a1.z, a1.w};
            float bv[8] = {b0.x, b0.y, b0.z, b0.w, b1.x, b1.y, b1.z, b1.w};
#pragma unroll
            for (int i = 0; i < 8; ++i)
#pragma unroll
                for (int j = 0; j < 8; ++j) acc[i][j] += av[i] * bv[j];
        }
        __syncthreads();
        if (tile + 1 < nt) store_tile();
        __syncthreads();
    }
#pragma unroll
    for (int i = 0; i < 8; ++i) {
        int row = bm + ((i < 4) ? (ty * 4 + i) : (64 + ty * 4 + i - 4));
        if (row >= M) continue;
#pragma unroll
        for (int j = 0; j < 8; ++j) {
            int col = bn + ((j < 4) ? (tx * 4 + j) : (64 + tx * 4 + j - 4));
            if (col >= N) continue;
            float v = acc[i][j];
            if (bias) v += bias[col];
            if (relu) v = fmaxf(v, 0.f);
            C[(size_t)row * ldc + col] = v;
        }
    }
}

// 64x64 tile, BK=16, 4x4 micro, reg prefetch — for the skinny M=512 GEMMs
__global__ __launch_bounds__(256) void k_gemm64(
    const float* __restrict__ A, const float* __restrict__ B,
    const float* __restrict__ bias, float* __restrict__ C,
    int M, int N, int K, int ldc, int relu) {
    __shared__ __align__(16) float As[16][64];
    __shared__ __align__(16) float Bs[16][64];
    const int bm = blockIdx.x * 64, bn = blockIdx.y * 64;
    const int tid = threadIdx.x;
    const int tx = tid & 15, ty = tid >> 4;
    const int arow = tid >> 2;
    const int akq  = (tid & 3) * 4;
    const int bkk  = tid >> 4;
    const int bc4  = (tid & 15) * 4;
    const int nt = (K + 15) / 16;
    float4 pa, pb;

    auto load_tile = [&](int k0) {
        int gr = bm + arow, gk = k0 + akq;
        float4 v = {0.f, 0.f, 0.f, 0.f};
        if (gr < M && gk + 4 <= K) v = *reinterpret_cast<const float4*>(&A[(size_t)gr * K + gk]);
        pa = v;
        int kk = k0 + bkk, gc = bn + bc4;
        float4 w = {0.f, 0.f, 0.f, 0.f};
        if (kk < K) {
            if (gc + 4 <= N) {
                w = *reinterpret_cast<const float4*>(&B[(size_t)kk * N + gc]);
            } else {
                float* wp = reinterpret_cast<float*>(&w);
                for (int j = 0; j < 4; ++j)
                    if (gc + j < N) wp[j] = B[(size_t)kk * N + gc + j];
            }
        }
        pb = w;
    };
    auto store_tile = [&]() {
        As[akq + 0][arow] = pa.x; As[akq + 1][arow] = pa.y;
        As[akq + 2][arow] = pa.z; As[akq + 3][arow] = pa.w;
        *reinterpret_cast<float4*>(&Bs[bkk][bc4]) = pb;
    };

    float acc[4][4] = {};
    load_tile(0);
    store_tile();
    __syncthreads();
    for (int tile = 0; tile < nt; ++tile) {
        if (tile + 1 < nt) load_tile((tile + 1) * 16);
#pragma unroll
        for (int kk = 0; kk < 16; ++kk) {
            float4 a = *reinterpret_cast<const float4*>(&As[kk][ty * 4]);
            float4 b = *reinterpret_cast<const float4*>(&Bs[kk][tx * 4]);
            float av[4] = {a.x, a.y, a.z, a.w};
            float bv[4] = {b.x, b.y, b.z, b.w};
#pragma unroll
            for (int i = 0; i < 4; ++i)
#pragma unroll
                for (int j = 0; j < 4; ++j) acc[i][j] += av[i] * bv[j];
        }
        __syncthreads();
        if (tile + 1 < nt) store_tile();
        __syncthreads();
    }
#pragma unroll
    for (int i = 0; i < 4; ++i) {
        int row = bm + ty * 4 + i;
        if (row >= M) continue;
#pragma unroll
        for (int j = 0; j < 4; ++j) {
            int col = bn + tx * 4 + j;
            if (col >= N) continue;
            float v = acc[i][j];
            if (bias) v += bias[col];
            if (relu) v = fmaxf(v, 0.f);
            C[(size_t)row * ldc + col] = v;
        }
    }
}

// ---------------------------------------------------------------- misc prep
__global__ void k_padx(const float* __restrict__ x, float* __restrict__ xp) {
    int i = blockIdx.x * blockDim.x + threadIdx.x;
    if (i >= NN * KPAD) return;
    int r = i / KPAD, c = i - r * KPAD;
    xp[i] = (c < FXD) ? x[r * FXD + c] : 0.f;
}

// ---------------------------------------------------------------- conv branch
// B[(v*8+k), p] = emb[v, p+k]
__global__ void k_bmat(const float* __restrict__ emb, float* __restrict__ Bm) {
    int b = blockIdx.x;          // 0..207
    int p = threadIdx.x;
    if (p >= CONVO) return;
    int v = b >> 3, k = b & 7;
    Bm[b * CONVO + p] = emb[v * EMBD + p + k];
}

// A[g][o][v][k] = sum_{s: target[g,s]==v} conv_W[o,s,k]  — bucket + reg accumulate
__global__ __launch_bounds__(256) void k_Amat(const int* __restrict__ target,
                                              const float* __restrict__ convW,
                                              float* __restrict__ Am) {
    __shared__ int vcnt[VOCAB];
    __shared__ int vfill[VOCAB];
    __shared__ int voff[VOCAB + 1];
    __shared__ int vpos[SEQ];
    const int g = blockIdx.x, tid = threadIdx.x;
    if (tid < VOCAB) { vcnt[tid] = 0; vfill[tid] = 0; }
    __syncthreads();
    const int* tg = target + (size_t)g * SEQ;
    for (int s = tid; s < SEQ; s += 256) atomicAdd(&vcnt[tg[s]], 1);
    __syncthreads();
    if (tid == 0) {
        int r = 0;
        for (int v = 0; v < VOCAB; ++v) { voff[v] = r; r += vcnt[v]; }
        voff[VOCAB] = r;
    }
    __syncthreads();
    for (int s = tid; s < SEQ; s += 256) {
        int v = tg[s];
        vpos[voff[v] + atomicAdd(&vfill[v], 1)] = s;
    }
    __syncthreads();
    const int o = tid >> 3, k = tid & 7;     // 256 threads = 32*8 exactly
    const float* wrow = convW + (size_t)o * (SEQ * KCONV) + k;
    float* arow = Am + (size_t)g * AROW + o * VK + k;
    for (int v = 0; v < VOCAB; ++v) {
        float r = 0.f;
        int p1 = voff[v + 1];
        for (int p = voff[v]; p < p1; ++p) r += wrow[(size_t)vpos[p] * KCONV];
        arow[v * KCONV] = r;
    }
}

// conv[g,o,p] = sum_vk A[g,o,vk] * B[vk,p] + conv_b[o]
__global__ __launch_bounds__(128) void k_conv(const float* __restrict__ Am,
                                              const float* __restrict__ Bm,
                                              const float* __restrict__ convb,
                                              float* __restrict__ out) {
    __shared__ float As[AROW];
    const int g = blockIdx.x, tid = threadIdx.x;
    for (int i = tid; i < AROW; i += 128) As[i] = Am[(size_t)g * AROW + i];
    __syncthreads();
    if (tid >= CONVO) return;
    const int p = tid;
    float acc[NFILT] = {};
    for (int vk = 0; vk < VK; ++vk) {
        float b = Bm[vk * CONVO + p];
#pragma unroll
        for (int o = 0; o < NFILT; ++o) acc[o] += As[o * VK + vk] * b;
    }
#pragma unroll
    for (int o = 0; o < NFILT; ++o)
        out[(size_t)g * (NFILT * CONVO) + o * CONVO + p] = acc[o] + convb[o];
}

// ---------------------------------------------------------------- launch
extern "C" void kernel_launch(void* const* d_in, const int* in_sizes, int n_in,
                              void* d_out, int out_size, void* d_ws, size_t ws_size,
                              hipStream_t stream) {
    const float* x        = (const float*)d_in[0];
    const int*   ei       = (const int*)d_in[1];
    const int*   batch    = (const int*)d_in[2];
    const int*   target   = (const int*)d_in[3];
    const float* gat_W    = (const float*)d_in[4];
    const float* gat_as   = (const float*)d_in[5];
    const float* gat_ad   = (const float*)d_in[6];
    const float* gat_b    = (const float*)d_in[7];
    const float* gcn_W    = (const float*)d_in[8];
    const float* gcn_b    = (const float*)d_in[9];
    const float* fcg1_W   = (const float*)d_in[10];
    const float* fcg1_b   = (const float*)d_in[11];
    const float* fcg2_W   = (const float*)d_in[12];
    const float* fcg2_b   = (const float*)d_in[13];
    const float* emb      = (const float*)d_in[14];
    const float* conv_W   = (const float*)d_in[15];
    const float* conv_b   = (const float*)d_in[16];
    const float* fcxt_W   = (const float*)d_in[17];
    const float* fcxt_b   = (const float*)d_in[18];
    const float* fc1_W    = (const float*)d_in[19];
    const float* fc1_b    = (const float*)d_in[20];
    const float* fc2_W    = (const float*)d_in[21];
    const float* fc2_b    = (const float*)d_in[22];
    const float* out_W    = (const float*)d_in[23];
    const float* out_b    = (const float*)d_in[24];
    float* outp = (float*)d_out;

    // ---- workspace layout ----
    const size_t BIG = (size_t)NN * HF;
    float* bigA   = (float*)d_ws;                 // h -> y -> small arena
    float* bigB   = bigA + BIG;                   // xp -> x1 -> x2
    float* asrc   = bigB + BIG;
    float* adst   = asrc + (size_t)NN * HEADS;
    float* mbuf   = adst + (size_t)NN * HEADS;
    float* dbuf   = mbuf + (size_t)NN * HEADS;
    float* dinv   = dbuf + (size_t)NN * HEADS;
    int* deg      = (int*)(dinv + NN);
    int* csr_off  = deg + NN;
    int* csr_fill = csr_off + (NN + 1);
    int* csr_src  = csr_fill + NN;
    int* gstart   = csr_src + NEP;
    // small arena aliased into bigA (free once y consumed by the GCN GEMM)
    float* pool    = bigA;                                  // 512*1560
    float* xg1     = pool + (size_t)NG * 2 * HF;            // 512*1024
    float* xc      = xg1 + (size_t)NG * 1024;               // 512*256
    float* f1      = xc + (size_t)NG * 256;                 // 512*1024
    float* f2      = f1 + (size_t)NG * 1024;                // 512*512
    float* Amat    = f2 + (size_t)NG * 512;                 // 512*6656
    float* Bmat    = Amat + (size_t)NG * AROW;              // 208*121
    float* convout = Bmat + (size_t)VK * CONVO;             // 512*3872
    float* xp      = bigB;                                  // 25000*80 (pre-x1)

    hipMemsetAsync(deg, 0, NN * sizeof(int), stream);
    hipMemsetAsync(csr_fill, 0, NN * sizeof(int), stream);

    // ---- GAT ----
    k_padx<<<(NN * KPAD + 255) / 256, 256, 0, stream>>>(x, xp);
    k_gemm128<<<dim3((NN + 127) / 128, (HF + 127) / 128), 256, 0, stream>>>(
        xp, gat_W, nullptr, bigA, NN, HF, KPAD, FXD, HF, 0);            // h = x@gat_W
    k_att<<<(NN + 3) / 4, 256, 0, stream>>>(bigA, gat_as, gat_ad, asrc, adst);
    k_deg<<<(NEP + 255) / 256, 256, 0, stream>>>(ei, deg);
    k_scan<<<1, 1024, 0, stream>>>(deg, csr_off);
    k_fill<<<(NEP + 255) / 256, 256, 0, stream>>>(ei, csr_off, csr_fill, csr_src);
    k_dinv<<<(NN + 255) / 256, 256, 0, stream>>>(deg, dinv);
    k_mden<<<(NN * HEADS + 255) / 256, 256, 0, stream>>>(csr_off, csr_src, asrc, adst, mbuf, dbuf);
    k_gat_feat<<<NN, 256, 0, stream>>>(csr_off, csr_src, asrc, adst, mbuf, dbuf,
                                       bigA, gat_b, bigB);              // x1
    // ---- GCN (aggregate first, then one dense GEMM) ----
    k_gcn_agg<<<NN, 256, 0, stream>>>(csr_off, csr_src, dinv, bigB, bigA);          // y
    k_gemm128<<<dim3((NN + 127) / 128, (HF + 127) / 128), 256, 0, stream>>>(
        bigA, gcn_W, gcn_b, bigB, NN, HF, HF, HF, HF, 1);               // x2

    // ---- pooling + graph MLP ----
    k_gstart<<<1, 1024, 0, stream>>>(batch, gstart);
    k_pool<<<NG, 256, 0, stream>>>(gstart, bigB, pool);
    k_gemm64<<<dim3(8, 16), 256, 0, stream>>>(pool, fcg1_W, fcg1_b, xg1, NG, 1024, 2 * HF, 1024, 1);
    k_gemm64<<<dim3(8, 2), 256, 0, stream>>>(xg1, fcg2_W, fcg2_b, xc, NG, 128, 1024, 256, 0);

    // ---- target CNN branch (vocab-factorized conv) ----
    k_bmat<<<VK, 128, 0, stream>>>(emb, Bmat);
    k_Amat<<<NG, 256, 0, stream>>>(target, conv_W, Amat);
    k_conv<<<NG, 128, 0, stream>>>(Amat, Bmat, conv_b, convout);
    k_gemm64<<<dim3(8, 2), 256, 0, stream>>>(convout, fcxt_W, fcxt_b, xc + 128, NG, 128,
                                             NFILT * CONVO, 256, 0);

    // ---- fusion head ----
    k_gemm64<<<dim3(8, 16), 256, 0, stream>>>(xc, fc1_W, fc1_b, f1, NG, 1024, 256, 1024, 1);
    k_gemm64<<<dim3(8, 8), 256, 0, stream>>>(f1, fc2_W, fc2_b, f2, NG, 512, 1024, 512, 1);
    k_gemm64<<<dim3(8, 1), 256, 0, stream>>>(f2, out_W, out_b, outp, NG, 1, 512, 1, 0);
}

// Round 3
// 1268.552 us; speedup vs baseline: 2.1048x; 1.5158x over previous
//
#include <hip/hip_runtime.h>
#include <cstdint>
#include <cstddef>

#define NN 25000        // nodes
#define NE 100000       // edges
#define NEP 125000      // edges + self loops
#define NG 512          // graphs
#define HEADS 10
#define FXD 78
#define HF 780          // HEADS*FXD
#define SEQ 1000
#define EMBD 128
#define NFILT 32
#define VOCAB 26
#define CONVO 121       // EMB-8+1
#define KCONV 8
#define VK (VOCAB*KCONV)     // 208
#define AROW (NFILT*VK)      // 6656
#define KP_GAT 80            // 78 padded to mult of 16
#define KP_GCN 784           // 780 padded to mult of 16

typedef unsigned short u16;
typedef short bf16x8 __attribute__((ext_vector_type(8)));
typedef float f32x4 __attribute__((ext_vector_type(4)));

// round-to-nearest-even bf16 split: v ~= hi + lo
__device__ inline void bsplit(float v, u16& h, u16& l) {
    unsigned u = __builtin_bit_cast(unsigned, v);
    unsigned hb = (u + 0x7fffu + ((u >> 16) & 1u)) >> 16;
    float fh = __builtin_bit_cast(float, hb << 16);
    float r = v - fh;
    unsigned u2 = __builtin_bit_cast(unsigned, r);
    unsigned lb = (u2 + 0x7fffu + ((u2 >> 16) & 1u)) >> 16;
    h = (u16)hb; l = (u16)lb;
}

// ---------------------------------------------------------------- CSR build
__global__ void k_deg(const int* __restrict__ ei, int* __restrict__ deg) {
    int e = blockIdx.x * blockDim.x + threadIdx.x;
    if (e >= NEP) return;
    int d = (e < NE) ? ei[NE + e] : (e - NE);
    atomicAdd(&deg[d], 1);
}

__global__ __launch_bounds__(1024) void k_scan(const int* __restrict__ deg, int* __restrict__ off) {
    __shared__ int tsum[1024];
    const int tid = threadIdx.x;
    const int base = tid * 25;
    int s = 0;
    for (int i = 0; i < 25; ++i) { int g = base + i; if (g < NN) s += deg[g]; }
    tsum[tid] = s;
    __syncthreads();
    for (int o = 1; o < 1024; o <<= 1) {
        int v = (tid >= o) ? tsum[tid - o] : 0;
        __syncthreads();
        tsum[tid] += v;
        __syncthreads();
    }
    int run = tid ? tsum[tid - 1] : 0;
    for (int i = 0; i < 25; ++i) {
        int g = base + i;
        if (g < NN) { off[g] = run; run += deg[g]; }
    }
    if (tid == 1023) off[NN] = tsum[1023];
}

__global__ void k_fill(const int* __restrict__ ei, const int* __restrict__ off,
                       int* __restrict__ fill, int* __restrict__ csrc) {
    int e = blockIdx.x * blockDim.x + threadIdx.x;
    if (e >= NEP) return;
    int s = (e < NE) ? ei[e]      : (e - NE);
    int d = (e < NE) ? ei[NE + e] : (e - NE);
    int pos = off[d] + atomicAdd(&fill[d], 1);
    csrc[pos] = s;
}

__global__ void k_dinv(const int* __restrict__ deg, float* __restrict__ dinv) {
    int n = blockIdx.x * blockDim.x + threadIdx.x;
    if (n >= NN) return;
    int dg = deg[n];
    dinv[n] = dg > 0 ? 1.0f / sqrtf((float)dg) : 0.0f;
}

// ---------------------------------------------------------------- split / transpose-split
// hi/lo[M][Kp] <- src[M][Ks], zero-padded k in [Ks,Kp)
__global__ void k_split(const float* __restrict__ src, u16* __restrict__ hi,
                        u16* __restrict__ lo, int M, int Ks, int Kp) {
    int half = Kp >> 1;
    int i = blockIdx.x * blockDim.x + threadIdx.x;
    if (i >= M * half) return;
    int m = i / half, kp = (i - m * half) * 2;
    const float* row = src + (size_t)m * Ks;
    float v0 = 0.f, v1 = 0.f;
    if (kp + 1 < Ks) { float2 t = *(const float2*)(row + kp); v0 = t.x; v1 = t.y; }
    else if (kp < Ks) v0 = row[kp];
    u16 h0, l0, h1, l1;
    bsplit(v0, h0, l0); bsplit(v1, h1, l1);
    size_t o = (size_t)m * Kp + kp;
    *(unsigned*)(hi + o) = (unsigned)h0 | ((unsigned)h1 << 16);
    *(unsigned*)(lo + o) = (unsigned)l0 | ((unsigned)l1 << 16);
}

// Th/Tl[N][Kp] <- W[K][N] transposed, zero-padded k in [K,Kp)
__global__ __launch_bounds__(256) void k_tsplit(const float* __restrict__ W,
                                                u16* __restrict__ Th, u16* __restrict__ Tl,
                                                int K, int N, int Kp) {
    __shared__ float tile[32][33];
    int n0 = blockIdx.x * 32, k0 = blockIdx.y * 32;
    int tx = threadIdx.x & 31, ty = threadIdx.x >> 5;   // 32x8
#pragma unroll
    for (int r = 0; r < 4; ++r) {
        int k = k0 + ty + r * 8, n = n0 + tx;
        tile[ty + r * 8][tx] = (k < K && n < N) ? W[(size_t)k * N + n] : 0.f;
    }
    __syncthreads();
#pragma unroll
    for (int r = 0; r < 4; ++r) {
        int nl = ty + r * 8, n = n0 + nl, k = k0 + tx;
        if (n < N && k < Kp) {
            u16 h, l;
            bsplit(tile[tx][nl], h, l);
            Th[(size_t)n * Kp + k] = h;
            Tl[(size_t)n * Kp + k] = l;
        }
    }
}

// ---------------------------------------------------------------- split-bf16 MFMA GEMM
// C[M][N](ldc) = act(A[M][Kp] @ Bt[N][Kp]^T + bias), A,Bt given as bf16 hi/lo pairs.
// 128x128 tile, 4 waves of 64x64, K-step 32, 16x16x32 MFMA, 3-product split.
__global__ __launch_bounds__(256, 2) void k_mfma_gemm(
    const u16* __restrict__ Ah, const u16* __restrict__ Al,
    const u16* __restrict__ Bh, const u16* __restrict__ Bl,
    const float* __restrict__ bias, float* __restrict__ C,
    int M, int N, int Kp, int ldc, int relu) {
    __shared__ __align__(16) u16 sAh[128][40];   // pad 32->40 u16 (80B rows)
    __shared__ __align__(16) u16 sAl[128][40];
    __shared__ __align__(16) u16 sBh[128][40];
    __shared__ __align__(16) u16 sBl[128][40];
    const int tid = threadIdx.x;
    const int bm = blockIdx.x * 128, bn = blockIdx.y * 128;
    const int lane = tid & 63, w = tid >> 6;
    const int wm = (w >> 1) * 64, wn = (w & 1) * 64;
    const int r16 = lane & 15, kb = (lane >> 4) * 8;
    const int srow = tid >> 1, shalf = tid & 1;
    const int arow = bm + srow, brow = bn + srow;
    const size_t aoff = (size_t)arow * Kp + shalf * 16;
    const size_t boff = (size_t)brow * Kp + shalf * 16;
    const int nsteps = (Kp + 31) / 32;

    uint4 pva[2], pvl[2], pvb[2], pwb[2];
    auto gload = [&](int s) {
        int k0 = s * 32;
        int kc = k0 + shalf * 16;
        bool kok = (kc + 16 <= Kp);
        uint4 z = {0, 0, 0, 0};
        pva[0] = pva[1] = pvl[0] = pvl[1] = z;
        pvb[0] = pvb[1] = pwb[0] = pwb[1] = z;
        if (kok && arow < M) {
            const uint4* p = (const uint4*)(Ah + aoff + k0);
            pva[0] = p[0]; pva[1] = p[1];
            const uint4* q = (const uint4*)(Al + aoff + k0);
            pvl[0] = q[0]; pvl[1] = q[1];
        }
        if (kok && brow < N) {
            const uint4* p = (const uint4*)(Bh + boff + k0);
            pvb[0] = p[0]; pvb[1] = p[1];
            const uint4* q = (const uint4*)(Bl + boff + k0);
            pwb[0] = q[0]; pwb[1] = q[1];
        }
    };

    f32x4 acc[4][4] = {};
    gload(0);
    for (int s = 0; s < nsteps; ++s) {
        __syncthreads();                       // prev compute done; LDS reusable
        {
            const int kk = shalf * 16;
            *(uint4*)&sAh[srow][kk] = pva[0]; *(uint4*)&sAh[srow][kk + 8] = pva[1];
            *(uint4*)&sAl[srow][kk] = pvl[0]; *(uint4*)&sAl[srow][kk + 8] = pvl[1];
            *(uint4*)&sBh[srow][kk] = pvb[0]; *(uint4*)&sBh[srow][kk + 8] = pvb[1];
            *(uint4*)&sBl[srow][kk] = pwb[0]; *(uint4*)&sBl[srow][kk + 8] = pwb[1];
        }
        __syncthreads();
        if (s + 1 < nsteps) gload(s + 1);      // prefetch overlaps compute
        bf16x8 fah[4], fal[4], fbh[4], fbl[4];
#pragma unroll
        for (int i = 0; i < 4; ++i) {
            fah[i] = *(const bf16x8*)&sAh[wm + i * 16 + r16][kb];
            fal[i] = *(const bf16x8*)&sAl[wm + i * 16 + r16][kb];
            fbh[i] = *(const bf16x8*)&sBh[wn + i * 16 + r16][kb];
            fbl[i] = *(const bf16x8*)&sBl[wn + i * 16 + r16][kb];
        }
#pragma unroll
        for (int i = 0; i < 4; ++i)
#pragma unroll
            for (int j = 0; j < 4; ++j) {
                acc[i][j] = __builtin_amdgcn_mfma_f32_16x16x32_bf16(fal[i], fbh[j], acc[i][j], 0, 0, 0);
                acc[i][j] = __builtin_amdgcn_mfma_f32_16x16x32_bf16(fah[i], fbl[j], acc[i][j], 0, 0, 0);
                acc[i][j] = __builtin_amdgcn_mfma_f32_16x16x32_bf16(fah[i], fbh[j], acc[i][j], 0, 0, 0);
            }
    }
    // epilogue: D col=lane&15, row=(lane>>4)*4+reg  [m89-verified]
    const int rbase = (lane >> 4) * 4;
#pragma unroll
    for (int j = 0; j < 4; ++j) {
        int col = bn + wn + j * 16 + r16;
        if (col >= N) continue;
        float bb = bias ? bias[col] : 0.f;
#pragma unroll
        for (int i = 0; i < 4; ++i) {
#pragma unroll
            for (int r = 0; r < 4; ++r) {
                int row = bm + wm + i * 16 + rbase + r;
                if (row < M) {
                    float v = acc[i][j][r] + bb;
                    if (relu) v = fmaxf(v, 0.f);
                    C[(size_t)row * ldc + col] = v;
                }
            }
        }
    }
}

// ---------------------------------------------------------------- GAT attention
__global__ void k_att(const float* __restrict__ h, const float* __restrict__ wsrc,
                      const float* __restrict__ wdst, float* __restrict__ asrc,
                      float* __restrict__ adst) {
    int node = blockIdx.x * 4 + (threadIdx.x >> 6);
    int lane = threadIdx.x & 63;
    if (node >= NN) return;
    const float* row = h + (size_t)node * HF;
    for (int hh = 0; hh < HEADS; ++hh) {
        float ps = 0.f, pd = 0.f;
        for (int f = lane; f < FXD; f += 64) {
            float v = row[hh * FXD + f];
            ps += v * wsrc[hh * FXD + f];
            pd += v * wdst[hh * FXD + f];
        }
        for (int o = 32; o > 0; o >>= 1) {
            ps += __shfl_down(ps, o);
            pd += __shfl_down(pd, o);
        }
        if (lane == 0) {
            asrc[node * HEADS + hh] = ps;
            adst[node * HEADS + hh] = pd;
        }
    }
}

__global__ void k_mden(const int* __restrict__ off, const int* __restrict__ csrc,
                       const float* __restrict__ asrc, const float* __restrict__ adst,
                       float* __restrict__ mbuf, float* __restrict__ dbuf) {
    int idx = blockIdx.x * blockDim.x + threadIdx.x;
    if (idx >= NN * HEADS) return;
    int d = idx / HEADS, hh = idx % HEADS;
    int s0 = off[d], s1 = off[d + 1];
    float ad = adst[idx];
    float m = -1e30f;
    for (int p = s0; p < s1; ++p) {
        float v = asrc[csrc[p] * HEADS + hh] + ad;
        v = v > 0.f ? v : 0.2f * v;
        m = fmaxf(m, v);
    }
    float den = 0.f;
    for (int p = s0; p < s1; ++p) {
        float v = asrc[csrc[p] * HEADS + hh] + ad;
        v = v > 0.f ? v : 0.2f * v;
        den += expf(v - m);
    }
    mbuf[idx] = m;
    dbuf[idx] = den;
}

// block per dst node: alpha inline, float4 feature MACs
__global__ __launch_bounds__(256) void k_gat_feat(
    const int* __restrict__ off, const int* __restrict__ csrc,
    const float* __restrict__ asrc, const float* __restrict__ adst,
    const float* __restrict__ mbuf, const float* __restrict__ dbuf,
    const float* __restrict__ h, const float* __restrict__ gat_b,
    float* __restrict__ x1) {
    __shared__ float lal[64 * HEADS];
    __shared__ int lsrc[64];
    __shared__ float s_ad[HEADS], s_m[HEADS], s_rd[HEADS];
    const int d = blockIdx.x, tid = threadIdx.x;
    if (tid < HEADS) {
        s_ad[tid] = adst[d * HEADS + tid];
        s_m[tid]  = mbuf[d * HEADS + tid];
        s_rd[tid] = 1.0f / (dbuf[d * HEADS + tid] + 1e-16f);
    }
    const int s0 = off[d], s1 = off[d + 1];
    int hj[4];
#pragma unroll
    for (int j = 0; j < 4; ++j) hj[j] = (tid < 195) ? (tid * 4 + j) / FXD : 0;
    float4 acc = {0.f, 0.f, 0.f, 0.f};
    for (int c0 = s0; c0 < s1; c0 += 64) {
        int cs = min(64, s1 - c0);
        __syncthreads();
        for (int i = tid; i < cs; i += 256) lsrc[i] = csrc[c0 + i];
        __syncthreads();
        for (int i = tid; i < cs * HEADS; i += 256) {
            int e = i / HEADS, hh = i - e * HEADS;
            float v = asrc[lsrc[e] * HEADS + hh] + s_ad[hh];
            v = v > 0.f ? v : 0.2f * v;
            lal[i] = __expf(v - s_m[hh]) * s_rd[hh];
        }
        __syncthreads();
        if (tid < 195) {
            for (int e = 0; e < cs; ++e) {
                const float4 hv = reinterpret_cast<const float4*>(h + (size_t)lsrc[e] * HF)[tid];
                const float* wv = &lal[e * HEADS];
                acc.x += wv[hj[0]] * hv.x;
                acc.y += wv[hj[1]] * hv.y;
                acc.z += wv[hj[2]] * hv.z;
                acc.w += wv[hj[3]] * hv.w;
            }
        }
    }
    if (tid < 195) {
        float4 b = reinterpret_cast<const float4*>(gat_b)[tid];
        float4 o;
        o.x = fmaxf(acc.x + b.x, 0.f);
        o.y = fmaxf(acc.y + b.y, 0.f);
        o.z = fmaxf(acc.z + b.z, 0.f);
        o.w = fmaxf(acc.w + b.w, 0.f);
        reinterpret_cast<float4*>(x1 + (size_t)d * HF)[tid] = o;
    }
}

// block per dst node: y[d,:] = sum_e dinv[s]*dinv[d]*x1[s,:]
__global__ __launch_bounds__(256) void k_gcn_agg(
    const int* __restrict__ off, const int* __restrict__ csrc,
    const float* __restrict__ dinv, const float* __restrict__ x1,
    float* __restrict__ y) {
    __shared__ float lno[256];
    __shared__ int lsrc[256];
    const int d = blockIdx.x, tid = threadIdx.x;
    const int s0 = off[d], s1 = off[d + 1];
    const float dd = dinv[d];
    float4 acc = {0.f, 0.f, 0.f, 0.f};
    for (int c0 = s0; c0 < s1; c0 += 256) {
        int cs = min(256, s1 - c0);
        __syncthreads();
        for (int i = tid; i < cs; i += 256) {
            int s = csrc[c0 + i];
            lsrc[i] = s;
            lno[i] = dinv[s] * dd;
        }
        __syncthreads();
        if (tid < 195) {
            for (int e = 0; e < cs; ++e) {
                const float4 v = reinterpret_cast<const float4*>(x1 + (size_t)lsrc[e] * HF)[tid];
                float wv = lno[e];
                acc.x += wv * v.x; acc.y += wv * v.y; acc.z += wv * v.z; acc.w += wv * v.w;
            }
        }
    }
    if (tid < 195) reinterpret_cast<float4*>(y + (size_t)d * HF)[tid] = acc;
}

// ---------------------------------------------------------------- pooling
__global__ void k_gstart(const int* __restrict__ batch, int* __restrict__ gstart) {
    int g = blockIdx.x * blockDim.x + threadIdx.x;
    if (g > NG) return;
    int lo = 0, hi = NN;
    while (lo < hi) {
        int mid = (lo + hi) >> 1;
        if (batch[mid] < g) lo = mid + 1; else hi = mid;
    }
    gstart[g] = lo;
}

__global__ __launch_bounds__(256) void k_pool(const int* __restrict__ gstart,
                                              const float* __restrict__ x2,
                                              float* __restrict__ pool) {
    const int g = blockIdx.x, tid = threadIdx.x;
    const int s0 = gstart[g], s1 = gstart[g + 1];
    if (tid >= 195) return;
    float4 mx = {0.f, 0.f, 0.f, 0.f};
    float4 sm = {0.f, 0.f, 0.f, 0.f};
    for (int n = s0; n < s1; ++n) {
        float4 v = reinterpret_cast<const float4*>(x2 + (size_t)n * HF)[tid];
        sm.x += v.x; sm.y += v.y; sm.z += v.z; sm.w += v.w;
        mx.x = fmaxf(mx.x, v.x); mx.y = fmaxf(mx.y, v.y);
        mx.z = fmaxf(mx.z, v.z); mx.w = fmaxf(mx.w, v.w);
    }
    float inv = 1.0f / (float)max(s1 - s0, 1);
    sm.x *= inv; sm.y *= inv; sm.z *= inv; sm.w *= inv;
    reinterpret_cast<float4*>(pool + (size_t)g * (2 * HF))[tid] = mx;
    reinterpret_cast<float4*>(pool + (size_t)g * (2 * HF) + HF)[tid] = sm;
}

// ---------------------------------------------------------------- small dense GEMM (M=512)
__global__ __launch_bounds__(256) void k_gemm64(
    const float* __restrict__ A, const float* __restrict__ B,
    const float* __restrict__ bias, float* __restrict__ C,
    int M, int N, int K, int ldc, int relu) {
    __shared__ __align__(16) float As[16][64];
    __shared__ __align__(16) float Bs[16][64];
    const int bm = blockIdx.x * 64, bn = blockIdx.y * 64;
    const int tid = threadIdx.x;
    const int tx = tid & 15, ty = tid >> 4;
    const int arow = tid >> 2;
    const int akq  = (tid & 3) * 4;
    const int bkk  = tid >> 4;
    const int bc4  = (tid & 15) * 4;
    const int nt = (K + 15) / 16;
    float4 pa, pb;

    auto load_tile = [&](int k0) {
        int gr = bm + arow, gk = k0 + akq;
        float4 v = {0.f, 0.f, 0.f, 0.f};
        if (gr < M && gk + 4 <= K) v = *reinterpret_cast<const float4*>(&A[(size_t)gr * K + gk]);
        pa = v;
        int kk = k0 + bkk, gc = bn + bc4;
        float4 wv = {0.f, 0.f, 0.f, 0.f};
        if (kk < K) {
            if (gc + 4 <= N) {
                wv = *reinterpret_cast<const float4*>(&B[(size_t)kk * N + gc]);
            } else {
                float* wp = reinterpret_cast<float*>(&wv);
                for (int j = 0; j < 4; ++j)
                    if (gc + j < N) wp[j] = B[(size_t)kk * N + gc + j];
            }
        }
        pb = wv;
    };
    auto store_tile = [&]() {
        As[akq + 0][arow] = pa.x; As[akq + 1][arow] = pa.y;
        As[akq + 2][arow] = pa.z; As[akq + 3][arow] = pa.w;
        *reinterpret_cast<float4*>(&Bs[bkk][bc4]) = pb;
    };

    float acc[4][4] = {};
    load_tile(0);
    store_tile();
    __syncthreads();
    for (int tile = 0; tile < nt; ++tile) {
        if (tile + 1 < nt) load_tile((tile + 1) * 16);
#pragma unroll
        for (int kk = 0; kk < 16; ++kk) {
            float4 a = *reinterpret_cast<const float4*>(&As[kk][ty * 4]);
            float4 b = *reinterpret_cast<const float4*>(&Bs[kk][tx * 4]);
            float av[4] = {a.x, a.y, a.z, a.w};
            float bv[4] = {b.x, b.y, b.z, b.w};
#pragma unroll
            for (int i = 0; i < 4; ++i)
#pragma unroll
                for (int j = 0; j < 4; ++j) acc[i][j] += av[i] * bv[j];
        }
        __syncthreads();
        if (tile + 1 < nt) store_tile();
        __syncthreads();
    }
#pragma unroll
    for (int i = 0; i < 4; ++i) {
        int row = bm + ty * 4 + i;
        if (row >= M) continue;
#pragma unroll
        for (int j = 0; j < 4; ++j) {
            int col = bn + tx * 4 + j;
            if (col >= N) continue;
            float v = acc[i][j];
            if (bias) v += bias[col];
            if (relu) v = fmaxf(v, 0.f);
            C[(size_t)row * ldc + col] = v;
        }
    }
}

// ---------------------------------------------------------------- conv branch
__global__ void k_bmat(const float* __restrict__ emb, float* __restrict__ Bm) {
    int b = blockIdx.x;          // 0..207
    int p = threadIdx.x;
    if (p >= CONVO) return;
    int v = b >> 3, k = b & 7;
    Bm[b * CONVO + p] = emb[v * EMBD + p + k];
}

__global__ __launch_bounds__(256) void k_Amat(const int* __restrict__ target,
                                              const float* __restrict__ convW,
                                              float* __restrict__ Am) {
    __shared__ int vcnt[VOCAB];
    __shared__ int vfill[VOCAB];
    __shared__ int voff[VOCAB + 1];
    __shared__ int vpos[SEQ];
    const int g = blockIdx.x, tid = threadIdx.x;
    if (tid < VOCAB) { vcnt[tid] = 0; vfill[tid] = 0; }
    __syncthreads();
    const int* tg = target + (size_t)g * SEQ;
    for (int s = tid; s < SEQ; s += 256) atomicAdd(&vcnt[tg[s]], 1);
    __syncthreads();
    if (tid == 0) {
        int r = 0;
        for (int v = 0; v < VOCAB; ++v) { voff[v] = r; r += vcnt[v]; }
        voff[VOCAB] = r;
    }
    __syncthreads();
    for (int s = tid; s < SEQ; s += 256) {
        int v = tg[s];
        vpos[voff[v] + atomicAdd(&vfill[v], 1)] = s;
    }
    __syncthreads();
    const int o = tid >> 3, k = tid & 7;
    const float* wrow = convW + (size_t)o * (SEQ * KCONV) + k;
    float* arow = Am + (size_t)g * AROW + o * VK + k;
    for (int v = 0; v < VOCAB; ++v) {
        float r = 0.f;
        int p1 = voff[v + 1];
        for (int p = voff[v]; p < p1; ++p) r += wrow[(size_t)vpos[p] * KCONV];
        arow[v * KCONV] = r;
    }
}

__global__ __launch_bounds__(128) void k_conv(const float* __restrict__ Am,
                                              const float* __restrict__ Bm,
                                              const float* __restrict__ convb,
                                              float* __restrict__ out) {
    __shared__ float As[AROW];
    const int g = blockIdx.x, tid = threadIdx.x;
    for (int i = tid; i < AROW; i += 128) As[i] = Am[(size_t)g * AROW + i];
    __syncthreads();
    if (tid >= CONVO) return;
    const int p = tid;
    float acc[NFILT] = {};
    for (int vk = 0; vk < VK; ++vk) {
        float b = Bm[vk * CONVO + p];
#pragma unroll
        for (int o = 0; o < NFILT; ++o) acc[o] += As[o * VK + vk] * b;
    }
#pragma unroll
    for (int o = 0; o < NFILT; ++o)
        out[(size_t)g * (NFILT * CONVO) + o * CONVO + p] = acc[o] + convb[o];
}

// ---------------------------------------------------------------- launch
extern "C" void kernel_launch(void* const* d_in, const int* in_sizes, int n_in,
                              void* d_out, int out_size, void* d_ws, size_t ws_size,
                              hipStream_t stream) {
    const float* x        = (const float*)d_in[0];
    const int*   ei       = (const int*)d_in[1];
    const int*   batch    = (const int*)d_in[2];
    const int*   target   = (const int*)d_in[3];
    const float* gat_W    = (const float*)d_in[4];
    const float* gat_as   = (const float*)d_in[5];
    const float* gat_ad   = (const float*)d_in[6];
    const float* gat_b    = (const float*)d_in[7];
    const float* gcn_W    = (const float*)d_in[8];
    const float* gcn_b    = (const float*)d_in[9];
    const float* fcg1_W   = (const float*)d_in[10];
    const float* fcg1_b   = (const float*)d_in[11];
    const float* fcg2_W   = (const float*)d_in[12];
    const float* fcg2_b   = (const float*)d_in[13];
    const float* emb      = (const float*)d_in[14];
    const float* conv_W   = (const float*)d_in[15];
    const float* conv_b   = (const float*)d_in[16];
    const float* fcxt_W   = (const float*)d_in[17];
    const float* fcxt_b   = (const float*)d_in[18];
    const float* fc1_W    = (const float*)d_in[19];
    const float* fc1_b    = (const float*)d_in[20];
    const float* fc2_W    = (const float*)d_in[21];
    const float* fc2_b    = (const float*)d_in[22];
    const float* out_W    = (const float*)d_in[23];
    const float* out_b    = (const float*)d_in[24];
    float* outp = (float*)d_out;

    // ---- workspace layout (float units) ----
    // R1: h -> y -> x2.  R2: x1 -> {yAh,yAl} -> small arena.
    float* R1   = (float*)d_ws;                       // 19,500,000
    float* R2   = R1 + 19500000;                      // 19,600,000
    float* xAf  = R2 + 19600000;                      // 2,000,000 (xAh+xAl)
    float* gWf  = xAf + 2000000;                      // 64,000
    float* cWf  = gWf + 64000;                        // 612,000
    float* asrc = cWf + 612000;
    float* adst = asrc + (size_t)NN * HEADS;
    float* mbuf = adst + (size_t)NN * HEADS;
    float* dbuf = mbuf + (size_t)NN * HEADS;
    float* dinv = dbuf + (size_t)NN * HEADS;
    int* deg      = (int*)(dinv + NN);
    int* csr_off  = deg + NN;
    int* csr_fill = csr_off + (NN + 1);
    int* csr_src  = csr_fill + NN;
    int* gstart   = csr_src + NEP;

    u16* xAh = (u16*)xAf;             u16* xAl = xAh + (size_t)NN * KP_GAT;
    u16* gWh = (u16*)gWf;             u16* gWl = gWh + (size_t)HF * KP_GAT;
    u16* cWh = (u16*)cWf;             u16* cWl = cWh + (size_t)HF * KP_GCN;
    u16* yAh = (u16*)R2;              u16* yAl = yAh + (size_t)NN * KP_GCN;

    // small arena in R2 (live only after GCN GEMM consumed yAh/yAl)
    float* pool    = R2;                                    // 512*1560
    float* xg1     = pool + (size_t)NG * 2 * HF;            // 512*1024
    float* xc      = xg1 + (size_t)NG * 1024;               // 512*256
    float* f1      = xc + (size_t)NG * 256;                 // 512*1024
    float* f2      = f1 + (size_t)NG * 1024;                // 512*512
    float* Amat    = f2 + (size_t)NG * 512;                 // 512*6656
    float* Bmat    = Amat + (size_t)NG * AROW;              // 208*121
    float* convout = Bmat + (size_t)VK * CONVO;             // 512*3872

    hipMemsetAsync(deg, 0, NN * sizeof(int), stream);
    hipMemsetAsync(csr_fill, 0, NN * sizeof(int), stream);

    // ---- GAT: h = x @ gat_W via split-bf16 MFMA ----
    k_split<<<(NN * (KP_GAT / 2) + 255) / 256, 256, 0, stream>>>(x, xAh, xAl, NN, FXD, KP_GAT);
    k_tsplit<<<dim3((HF + 31) / 32, (KP_GAT + 31) / 32), 256, 0, stream>>>(
        gat_W, gWh, gWl, FXD, HF, KP_GAT);
    k_mfma_gemm<<<dim3((NN + 127) / 128, (HF + 127) / 128), 256, 0, stream>>>(
        xAh, xAl, gWh, gWl, nullptr, R1, NN, HF, KP_GAT, HF, 0);        // h -> R1

    k_att<<<(NN + 3) / 4, 256, 0, stream>>>(R1, gat_as, gat_ad, asrc, adst);
    k_deg<<<(NEP + 255) / 256, 256, 0, stream>>>(ei, deg);
    k_scan<<<1, 1024, 0, stream>>>(deg, csr_off);
    k_fill<<<(NEP + 255) / 256, 256, 0, stream>>>(ei, csr_off, csr_fill, csr_src);
    k_dinv<<<(NN + 255) / 256, 256, 0, stream>>>(deg, dinv);
    k_mden<<<(NN * HEADS + 255) / 256, 256, 0, stream>>>(csr_off, csr_src, asrc, adst, mbuf, dbuf);
    k_gat_feat<<<NN, 256, 0, stream>>>(csr_off, csr_src, asrc, adst, mbuf, dbuf,
                                       R1, gat_b, R2);                  // x1 -> R2

    // ---- GCN: aggregate, split, one MFMA GEMM ----
    k_gcn_agg<<<NN, 256, 0, stream>>>(csr_off, csr_src, dinv, R2, R1);  // y -> R1
    k_split<<<(NN * (KP_GCN / 2) + 255) / 256, 256, 0, stream>>>(R1, yAh, yAl, NN, HF, KP_GCN);
    k_tsplit<<<dim3((HF + 31) / 32, (KP_GCN + 31) / 32), 256, 0, stream>>>(
        gcn_W, cWh, cWl, HF, HF, KP_GCN);
    k_mfma_gemm<<<dim3((NN + 127) / 128, (HF + 127) / 128), 256, 0, stream>>>(
        yAh, yAl, cWh, cWl, gcn_b, R1, NN, HF, KP_GCN, HF, 1);          // x2 -> R1

    // ---- pooling + graph MLP ----
    k_gstart<<<1, 1024, 0, stream>>>(batch, gstart);
    k_pool<<<NG, 256, 0, stream>>>(gstart, R1, pool);
    k_gemm64<<<dim3(8, 16), 256, 0, stream>>>(pool, fcg1_W, fcg1_b, xg1, NG, 1024, 2 * HF, 1024, 1);
    k_gemm64<<<dim3(8, 2), 256, 0, stream>>>(xg1, fcg2_W, fcg2_b, xc, NG, 128, 1024, 256, 0);

    // ---- target CNN branch (vocab-factorized conv) ----
    k_bmat<<<VK, 128, 0, stream>>>(emb, Bmat);
    k_Amat<<<NG, 256, 0, stream>>>(target, conv_W, Amat);
    k_conv<<<NG, 128, 0, stream>>>(Amat, Bmat, conv_b, convout);
    k_gemm64<<<dim3(8, 2), 256, 0, stream>>>(convout, fcxt_W, fcxt_b, xc + 128, NG, 128,
                                             NFILT * CONVO, 256, 0);

    // ---- fusion head ----
    k_gemm64<<<dim3(8, 16), 256, 0, stream>>>(xc, fc1_W, fc1_b, f1, NG, 1024, 256, 1024, 1);
    k_gemm64<<<dim3(8, 8), 256, 0, stream>>>(f1, fc2_W, fc2_b, f2, NG, 512, 1024, 512, 1);
    k_gemm64<<<dim3(8, 1), 256, 0, stream>>>(f2, out_W, out_b, outp, NG, 1, 512, 1, 0);
}

// Round 7
// 888.016 us; speedup vs baseline: 3.0067x; 1.4285x over previous
//
#include <hip/hip_runtime.h>
#include <cstdint>
#include <cstddef>

#define NN 25000        // nodes
#define NE 100000       // edges
#define NEP 125000      // edges + self loops
#define NG 512          // graphs
#define HEADS 10
#define FXD 78
#define HF 780          // HEADS*FXD
#define SEQ 1000
#define EMBD 128
#define NFILT 32
#define VOCAB 26
#define CONVO 121       // EMB-8+1
#define KCONV 8
#define VK (VOCAB*KCONV)     // 208
#define AROW (NFILT*VK)      // 6656
#define KP_GAT 80            // 78 padded to mult of 16
#define KP_GCN 784           // 780 padded to mult of 16

typedef unsigned short u16;
typedef short bf16x8 __attribute__((ext_vector_type(8)));
typedef float f32x4 __attribute__((ext_vector_type(4)));

// round-to-nearest-even bf16 split: v ~= hi + lo
__device__ inline void bsplit(float v, u16& h, u16& l) {
    unsigned u = __builtin_bit_cast(unsigned, v);
    unsigned hb = (u + 0x7fffu + ((u >> 16) & 1u)) >> 16;
    float fh = __builtin_bit_cast(float, hb << 16);
    float r = v - fh;
    unsigned u2 = __builtin_bit_cast(unsigned, r);
    unsigned lb = (u2 + 0x7fffu + ((u2 >> 16) & 1u)) >> 16;
    h = (u16)hb; l = (u16)lb;
}

// ---------------------------------------------------------------- CSR build
__global__ void k_deg(const int* __restrict__ ei, int* __restrict__ deg) {
    int e = blockIdx.x * blockDim.x + threadIdx.x;
    if (e >= NEP) return;
    int d = (e < NE) ? ei[NE + e] : (e - NE);
    atomicAdd(&deg[d], 1);
}

__global__ __launch_bounds__(1024) void k_scan(const int* __restrict__ deg, int* __restrict__ off) {
    __shared__ int tsum[1024];
    const int tid = threadIdx.x;
    const int base = tid * 25;
    int s = 0;
    for (int i = 0; i < 25; ++i) { int g = base + i; if (g < NN) s += deg[g]; }
    tsum[tid] = s;
    __syncthreads();
    for (int o = 1; o < 1024; o <<= 1) {
        int v = (tid >= o) ? tsum[tid - o] : 0;
        __syncthreads();
        tsum[tid] += v;
        __syncthreads();
    }
    int run = tid ? tsum[tid - 1] : 0;
    for (int i = 0; i < 25; ++i) {
        int g = base + i;
        if (g < NN) { off[g] = run; run += deg[g]; }
    }
    if (tid == 1023) off[NN] = tsum[1023];
}

__global__ void k_fill(const int* __restrict__ ei, const int* __restrict__ off,
                       int* __restrict__ fill, int* __restrict__ csrc) {
    int e = blockIdx.x * blockDim.x + threadIdx.x;
    if (e >= NEP) return;
    int s = (e < NE) ? ei[e]      : (e - NE);
    int d = (e < NE) ? ei[NE + e] : (e - NE);
    int pos = off[d] + atomicAdd(&fill[d], 1);
    csrc[pos] = s;
}

__global__ void k_dinv(const int* __restrict__ deg, float* __restrict__ dinv) {
    int n = blockIdx.x * blockDim.x + threadIdx.x;
    if (n >= NN) return;
    int dg = deg[n];
    dinv[n] = dg > 0 ? 1.0f / sqrtf((float)dg) : 0.0f;
}

// ---------------------------------------------------------------- split / transpose-split
__global__ void k_split(const float* __restrict__ src, u16* __restrict__ hi,
                        u16* __restrict__ lo, int M, int Ks, int Kp) {
    int half = Kp >> 1;
    int i = blockIdx.x * blockDim.x + threadIdx.x;
    if (i >= M * half) return;
    int m = i / half, kp = (i - m * half) * 2;
    const float* row = src + (size_t)m * Ks;
    float v0 = 0.f, v1 = 0.f;
    if (kp + 1 < Ks) { float2 t = *(const float2*)(row + kp); v0 = t.x; v1 = t.y; }
    else if (kp < Ks) v0 = row[kp];
    u16 h0, l0, h1, l1;
    bsplit(v0, h0, l0); bsplit(v1, h1, l1);
    size_t o = (size_t)m * Kp + kp;
    *(unsigned*)(hi + o) = (unsigned)h0 | ((unsigned)h1 << 16);
    *(unsigned*)(lo + o) = (unsigned)l0 | ((unsigned)l1 << 16);
}

// Th/Tl[N][Kp] <- W[K][N] transposed, zero-padded k in [K,Kp)
__global__ __launch_bounds__(256) void k_tsplit(const float* __restrict__ W,
                                                u16* __restrict__ Th, u16* __restrict__ Tl,
                                                int K, int N, int Kp) {
    __shared__ float tile[32][33];
    int n0 = blockIdx.x * 32, k0 = blockIdx.y * 32;
    int tx = threadIdx.x & 31, ty = threadIdx.x >> 5;   // 32x8
#pragma unroll
    for (int r = 0; r < 4; ++r) {
        int k = k0 + ty + r * 8, n = n0 + tx;
        tile[ty + r * 8][tx] = (k < K && n < N) ? W[(size_t)k * N + n] : 0.f;
    }
    __syncthreads();
#pragma unroll
    for (int r = 0; r < 4; ++r) {
        int nl = ty + r * 8, n = n0 + nl, k = k0 + tx;
        if (n < N && k < Kp) {
            u16 h, l;
            bsplit(tile[tx][nl], h, l);
            Th[(size_t)n * Kp + k] = h;
            Tl[(size_t)n * Kp + k] = l;
        }
    }
}

// ---------------------------------------------------------------- split-bf16 MFMA GEMM
__global__ __launch_bounds__(256, 2) void k_mfma_gemm(
    const u16* __restrict__ Ah, const u16* __restrict__ Al,
    const u16* __restrict__ Bh, const u16* __restrict__ Bl,
    const float* __restrict__ bias, float* __restrict__ C,
    int M, int N, int Kp, int ldc, int relu) {
    __shared__ __align__(16) u16 sAh[128][40];
    __shared__ __align__(16) u16 sAl[128][40];
    __shared__ __align__(16) u16 sBh[128][40];
    __shared__ __align__(16) u16 sBl[128][40];
    const int tid = threadIdx.x;
    const int bm = blockIdx.x * 128, bn = blockIdx.y * 128;
    const int lane = tid & 63, w = tid >> 6;
    const int wm = (w >> 1) * 64, wn = (w & 1) * 64;
    const int r16 = lane & 15, kb = (lane >> 4) * 8;
    const int srow = tid >> 1, shalf = tid & 1;
    const int arow = bm + srow, brow = bn + srow;
    const size_t aoff = (size_t)arow * Kp + shalf * 16;
    const size_t boff = (size_t)brow * Kp + shalf * 16;
    const int nsteps = (Kp + 31) / 32;

    uint4 pva[2], pvl[2], pvb[2], pwb[2];
    auto gload = [&](int s) {
        int k0 = s * 32;
        int kc = k0 + shalf * 16;
        bool kok = (kc + 16 <= Kp);
        uint4 z = {0, 0, 0, 0};
        pva[0] = pva[1] = pvl[0] = pvl[1] = z;
        pvb[0] = pvb[1] = pwb[0] = pwb[1] = z;
        if (kok && arow < M) {
            const uint4* p = (const uint4*)(Ah + aoff + k0);
            pva[0] = p[0]; pva[1] = p[1];
            const uint4* q = (const uint4*)(Al + aoff + k0);
            pvl[0] = q[0]; pvl[1] = q[1];
        }
        if (kok && brow < N) {
            const uint4* p = (const uint4*)(Bh + boff + k0);
            pvb[0] = p[0]; pvb[1] = p[1];
            const uint4* q = (const uint4*)(Bl + boff + k0);
            pwb[0] = q[0]; pwb[1] = q[1];
        }
    };

    f32x4 acc[4][4] = {};
    gload(0);
    for (int s = 0; s < nsteps; ++s) {
        __syncthreads();
        {
            const int kk = shalf * 16;
            *(uint4*)&sAh[srow][kk] = pva[0]; *(uint4*)&sAh[srow][kk + 8] = pva[1];
            *(uint4*)&sAl[srow][kk] = pvl[0]; *(uint4*)&sAl[srow][kk + 8] = pvl[1];
            *(uint4*)&sBh[srow][kk] = pvb[0]; *(uint4*)&sBh[srow][kk + 8] = pvb[1];
            *(uint4*)&sBl[srow][kk] = pwb[0]; *(uint4*)&sBl[srow][kk + 8] = pwb[1];
        }
        __syncthreads();
        if (s + 1 < nsteps) gload(s + 1);
        bf16x8 fah[4], fal[4], fbh[4], fbl[4];
#pragma unroll
        for (int i = 0; i < 4; ++i) {
            fah[i] = *(const bf16x8*)&sAh[wm + i * 16 + r16][kb];
            fal[i] = *(const bf16x8*)&sAl[wm + i * 16 + r16][kb];
            fbh[i] = *(const bf16x8*)&sBh[wn + i * 16 + r16][kb];
            fbl[i] = *(const bf16x8*)&sBl[wn + i * 16 + r16][kb];
        }
#pragma unroll
        for (int i = 0; i < 4; ++i)
#pragma unroll
            for (int j = 0; j < 4; ++j) {
                acc[i][j] = __builtin_amdgcn_mfma_f32_16x16x32_bf16(fal[i], fbh[j], acc[i][j], 0, 0, 0);
                acc[i][j] = __builtin_amdgcn_mfma_f32_16x16x32_bf16(fah[i], fbl[j], acc[i][j], 0, 0, 0);
                acc[i][j] = __builtin_amdgcn_mfma_f32_16x16x32_bf16(fah[i], fbh[j], acc[i][j], 0, 0, 0);
            }
    }
    const int rbase = (lane >> 4) * 4;
#pragma unroll
    for (int j = 0; j < 4; ++j) {
        int col = bn + wn + j * 16 + r16;
        if (col >= N) continue;
        float bb = bias ? bias[col] : 0.f;
#pragma unroll
        for (int i = 0; i < 4; ++i) {
#pragma unroll
            for (int r = 0; r < 4; ++r) {
                int row = bm + wm + i * 16 + rbase + r;
                if (row < M) {
                    float v = acc[i][j][r] + bb;
                    if (relu) v = fmaxf(v, 0.f);
                    C[(size_t)row * ldc + col] = v;
                }
            }
        }
    }
}

// ---------------------------------------------------------------- GAT attention
__global__ void k_att(const float* __restrict__ h, const float* __restrict__ wsrc,
                      const float* __restrict__ wdst, float* __restrict__ asrc,
                      float* __restrict__ adst) {
    int node = blockIdx.x * 4 + (threadIdx.x >> 6);
    int lane = threadIdx.x & 63;
    if (node >= NN) return;
    const float* row = h + (size_t)node * HF;
    for (int hh = 0; hh < HEADS; ++hh) {
        float ps = 0.f, pd = 0.f;
        for (int f = lane; f < FXD; f += 64) {
            float v = row[hh * FXD + f];
            ps += v * wsrc[hh * FXD + f];
            pd += v * wdst[hh * FXD + f];
        }
        for (int o = 32; o > 0; o >>= 1) {
            ps += __shfl_down(ps, o);
            pd += __shfl_down(pd, o);
        }
        if (lane == 0) {
            asrc[node * HEADS + hh] = ps;
            adst[node * HEADS + hh] = pd;
        }
    }
}

__global__ void k_mden(const int* __restrict__ off, const int* __restrict__ csrc,
                       const float* __restrict__ asrc, const float* __restrict__ adst,
                       float* __restrict__ mbuf, float* __restrict__ dbuf) {
    int idx = blockIdx.x * blockDim.x + threadIdx.x;
    if (idx >= NN * HEADS) return;
    int d = idx / HEADS, hh = idx % HEADS;
    int s0 = off[d], s1 = off[d + 1];
    float ad = adst[idx];
    float m = -1e30f;
    for (int p = s0; p < s1; ++p) {
        float v = asrc[csrc[p] * HEADS + hh] + ad;
        v = v > 0.f ? v : 0.2f * v;
        m = fmaxf(m, v);
    }
    float den = 0.f;
    for (int p = s0; p < s1; ++p) {
        float v = asrc[csrc[p] * HEADS + hh] + ad;
        v = v > 0.f ? v : 0.2f * v;
        den += expf(v - m);
    }
    mbuf[idx] = m;
    dbuf[idx] = den;
}

// block per dst node: alpha inline, float4 feature MACs
__global__ __launch_bounds__(256) void k_gat_feat(
    const int* __restrict__ off, const int* __restrict__ csrc,
    const float* __restrict__ asrc, const float* __restrict__ adst,
    const float* __restrict__ mbuf, const float* __restrict__ dbuf,
    const float* __restrict__ h, const float* __restrict__ gat_b,
    float* __restrict__ x1) {
    __shared__ float lal[64 * HEADS];
    __shared__ int lsrc[64];
    __shared__ float s_ad[HEADS], s_m[HEADS], s_rd[HEADS];
    const int d = blockIdx.x, tid = threadIdx.x;
    if (tid < HEADS) {
        s_ad[tid] = adst[d * HEADS + tid];
        s_m[tid]  = mbuf[d * HEADS + tid];
        s_rd[tid] = 1.0f / (dbuf[d * HEADS + tid] + 1e-16f);
    }
    const int s0 = off[d], s1 = off[d + 1];
    int hj[4];
#pragma unroll
    for (int j = 0; j < 4; ++j) hj[j] = (tid < 195) ? (tid * 4 + j) / FXD : 0;
    float4 acc = {0.f, 0.f, 0.f, 0.f};
    for (int c0 = s0; c0 < s1; c0 += 64) {
        int cs = min(64, s1 - c0);
        __syncthreads();
        for (int i = tid; i < cs; i += 256) lsrc[i] = csrc[c0 + i];
        __syncthreads();
        for (int i = tid; i < cs * HEADS; i += 256) {
            int e = i / HEADS, hh = i - e * HEADS;
            float v = asrc[lsrc[e] * HEADS + hh] + s_ad[hh];
            v = v > 0.f ? v : 0.2f * v;
            lal[i] = __expf(v - s_m[hh]) * s_rd[hh];
        }
        __syncthreads();
        if (tid < 195) {
            for (int e = 0; e < cs; ++e) {
                const float4 hv = reinterpret_cast<const float4*>(h + (size_t)lsrc[e] * HF)[tid];
                const float* wv = &lal[e * HEADS];
                acc.x += wv[hj[0]] * hv.x;
                acc.y += wv[hj[1]] * hv.y;
                acc.z += wv[hj[2]] * hv.z;
                acc.w += wv[hj[3]] * hv.w;
            }
        }
    }
    if (tid < 195) {
        float4 b = reinterpret_cast<const float4*>(gat_b)[tid];
        float4 o;
        o.x = fmaxf(acc.x + b.x, 0.f);
        o.y = fmaxf(acc.y + b.y, 0.f);
        o.z = fmaxf(acc.z + b.z, 0.f);
        o.w = fmaxf(acc.w + b.w, 0.f);
        reinterpret_cast<float4*>(x1 + (size_t)d * HF)[tid] = o;
    }
}

// block per dst node: y = sum_e dinv[s]*dinv[d]*x1[s,:], bf16-split inline
__global__ __launch_bounds__(256) void k_gcn_agg(
    const int* __restrict__ off, const int* __restrict__ csrc,
    const float* __restrict__ dinv, const float* __restrict__ x1,
    u16* __restrict__ yAh, u16* __restrict__ yAl) {
    __shared__ float lno[256];
    __shared__ int lsrc[256];
    const int d = blockIdx.x, tid = threadIdx.x;
    const int s0 = off[d], s1 = off[d + 1];
    const float dd = dinv[d];
    float4 acc = {0.f, 0.f, 0.f, 0.f};
    for (int c0 = s0; c0 < s1; c0 += 256) {
        int cs = min(256, s1 - c0);
        __syncthreads();
        for (int i = tid; i < cs; i += 256) {
            int s = csrc[c0 + i];
            lsrc[i] = s;
            lno[i] = dinv[s] * dd;
        }
        __syncthreads();
        if (tid < 195) {
            for (int e = 0; e < cs; ++e) {
                const float4 v = reinterpret_cast<const float4*>(x1 + (size_t)lsrc[e] * HF)[tid];
                float wv = lno[e];
                acc.x += wv * v.x; acc.y += wv * v.y; acc.z += wv * v.z; acc.w += wv * v.w;
            }
        }
    }
    if (tid < 195) {
        ushort4 hv, lv;
        bsplit(acc.x, hv.x, lv.x); bsplit(acc.y, hv.y, lv.y);
        bsplit(acc.z, hv.z, lv.z); bsplit(acc.w, hv.w, lv.w);
        *reinterpret_cast<ushort4*>(yAh + (size_t)d * KP_GCN + tid * 4) = hv;
        *reinterpret_cast<ushort4*>(yAl + (size_t)d * KP_GCN + tid * 4) = lv;
    } else if (tid == 195) {
        ushort4 z = {0, 0, 0, 0};
        *reinterpret_cast<ushort4*>(yAh + (size_t)d * KP_GCN + 780) = z;
        *reinterpret_cast<ushort4*>(yAl + (size_t)d * KP_GCN + 780) = z;
    }
}

// ---------------------------------------------------------------- pooling
__global__ void k_gstart(const int* __restrict__ batch, int* __restrict__ gstart) {
    int g = blockIdx.x * blockDim.x + threadIdx.x;
    if (g > NG) return;
    int lo = 0, hi = NN;
    while (lo < hi) {
        int mid = (lo + hi) >> 1;
        if (batch[mid] < g) lo = mid + 1; else hi = mid;
    }
    gstart[g] = lo;
}

__global__ __launch_bounds__(256) void k_pool(const int* __restrict__ gstart,
                                              const float* __restrict__ x2,
                                              float* __restrict__ pool) {
    const int g = blockIdx.x, tid = threadIdx.x;
    const int s0 = gstart[g], s1 = gstart[g + 1];
    if (tid >= 195) return;
    float4 mx = {0.f, 0.f, 0.f, 0.f};
    float4 sm = {0.f, 0.f, 0.f, 0.f};
    for (int n = s0; n < s1; ++n) {
        float4 v = reinterpret_cast<const float4*>(x2 + (size_t)n * HF)[tid];
        sm.x += v.x; sm.y += v.y; sm.z += v.z; sm.w += v.w;
        mx.x = fmaxf(mx.x, v.x); mx.y = fmaxf(mx.y, v.y);
        mx.z = fmaxf(mx.z, v.z); mx.w = fmaxf(mx.w, v.w);
    }
    float inv = 1.0f / (float)max(s1 - s0, 1);
    sm.x *= inv; sm.y *= inv; sm.z *= inv; sm.w *= inv;
    reinterpret_cast<float4*>(pool + (size_t)g * (2 * HF))[tid] = mx;
    reinterpret_cast<float4*>(pool + (size_t)g * (2 * HF) + HF)[tid] = sm;
}

// ---------------------------------------------------------------- split-K head GEMMs
__global__ __launch_bounds__(256) void k_gemm_sk(
    const float* __restrict__ A, const float* __restrict__ B,
    float* __restrict__ P, int M, int N, int K, int KS) {
    __shared__ __align__(16) float As[16][64];
    __shared__ __align__(16) float Bs[16][64];
    const int bm = blockIdx.x * 64, bn = blockIdx.y * 64;
    const int s = blockIdx.z;
    const int k0 = s * KS, k1 = min(k0 + KS, K);
    const int tid = threadIdx.x;
    const int tx = tid & 15, ty = tid >> 4;
    const int arow = tid >> 2, akq = (tid & 3) * 4;
    const int bkk = tid >> 4, bc4 = (tid & 15) * 4;
    float acc[4][4] = {};
    for (int kt = k0; kt < k1; kt += 16) {
        __syncthreads();
        {
            int gk = kt + akq;
            float4 v = {0.f, 0.f, 0.f, 0.f};
            if (gk + 4 <= k1) v = *reinterpret_cast<const float4*>(&A[(size_t)(bm + arow) * K + gk]);
            As[akq + 0][arow] = v.x; As[akq + 1][arow] = v.y;
            As[akq + 2][arow] = v.z; As[akq + 3][arow] = v.w;
            int kk = kt + bkk;
            float4 wv = {0.f, 0.f, 0.f, 0.f};
            if (kk < k1) wv = *reinterpret_cast<const float4*>(&B[(size_t)kk * N + bn + bc4]);
            *reinterpret_cast<float4*>(&Bs[bkk][bc4]) = wv;
        }
        __syncthreads();
#pragma unroll
        for (int kk = 0; kk < 16; ++kk) {
            float4 a = *reinterpret_cast<const float4*>(&As[kk][ty * 4]);
            float4 b = *reinterpret_cast<const float4*>(&Bs[kk][tx * 4]);
            float av[4] = {a.x, a.y, a.z, a.w};
            float bv[4] = {b.x, b.y, b.z, b.w};
#pragma unroll
            for (int i = 0; i < 4; ++i)
#pragma unroll
                for (int j = 0; j < 4; ++j) acc[i][j] += av[i] * bv[j];
        }
    }
    float* Pr = P + (size_t)s * M * N;
#pragma unroll
    for (int i = 0; i < 4; ++i) {
        int row = bm + ty * 4 + i;
        float4 v = {acc[i][0], acc[i][1], acc[i][2], acc[i][3]};
        *reinterpret_cast<float4*>(&Pr[(size_t)row * N + bn + tx * 4]) = v;
    }
}

__global__ void k_reduce(const float* __restrict__ P, const float* __restrict__ bias,
                         float* __restrict__ C, int M, int N, int S, int ldc, int relu) {
    int i = blockIdx.x * blockDim.x + threadIdx.x;
    int nq = N >> 2;
    if (i >= M * nq) return;
    int m = i / nq, c4 = (i - m * nq) * 4;
    const float4* p = reinterpret_cast<const float4*>(P) + i;
    size_t stride4 = (size_t)M * nq;
    float4 a = p[0];
    for (int s = 1; s < S; ++s) {
        float4 v = p[(size_t)s * stride4];
        a.x += v.x; a.y += v.y; a.z += v.z; a.w += v.w;
    }
    float4 b = *reinterpret_cast<const float4*>(bias + c4);
    a.x += b.x; a.y += b.y; a.z += b.z; a.w += b.w;
    if (relu) {
        a.x = fmaxf(a.x, 0.f); a.y = fmaxf(a.y, 0.f);
        a.z = fmaxf(a.z, 0.f); a.w = fmaxf(a.w, 0.f);
    }
    *reinterpret_cast<float4*>(&C[(size_t)m * ldc + c4]) = a;
}

__global__ void k_gemv_out(const float* __restrict__ A, const float* __restrict__ w,
                           const float* __restrict__ b, float* __restrict__ out) {
    int m = blockIdx.x * 4 + (threadIdx.x >> 6);
    int lane = threadIdx.x & 63;
    if (m >= NG) return;
    const float* row = A + (size_t)m * 512;
    float p = 0.f;
#pragma unroll
    for (int t = 0; t < 8; ++t) p += row[lane + t * 64] * w[lane + t * 64];
    for (int o = 32; o > 0; o >>= 1) p += __shfl_down(p, o);
    if (lane == 0) out[m] = p + b[0];
}

// ---------------------------------------------------------------- conv branch
__global__ void k_bmat(const float* __restrict__ emb, float* __restrict__ Bm) {
    int b = blockIdx.x;          // 0..207
    int p = threadIdx.x;
    if (p >= CONVO) return;
    int v = b >> 3, k = b & 7;
    Bm[b * CONVO + p] = emb[v * EMBD + p + k];
}

__global__ __launch_bounds__(256) void k_Amat(const int* __restrict__ target,
                                              const float* __restrict__ convW,
                                              float* __restrict__ Am) {
    __shared__ int vcnt[VOCAB];
    __shared__ int vfill[VOCAB];
    __shared__ int voff[VOCAB + 1];
    __shared__ int vpos[SEQ];
    const int g = blockIdx.x, tid = threadIdx.x;
    if (tid < VOCAB) { vcnt[tid] = 0; vfill[tid] = 0; }
    __syncthreads();
    const int* tg = target + (size_t)g * SEQ;
    for (int s = tid; s < SEQ; s += 256) atomicAdd(&vcnt[tg[s]], 1);
    __syncthreads();
    if (tid == 0) {
        int r = 0;
        for (int v = 0; v < VOCAB; ++v) { voff[v] = r; r += vcnt[v]; }
        voff[VOCAB] = r;
    }
    __syncthreads();
    for (int s = tid; s < SEQ; s += 256) {
        int v = tg[s];
        vpos[voff[v] + atomicAdd(&vfill[v], 1)] = s;
    }
    __syncthreads();
    const int o = tid >> 3, k = tid & 7;
    const float* wrow = convW + (size_t)o * (SEQ * KCONV) + k;
    float* arow = Am + (size_t)g * AROW + o * VK + k;
    for (int v = 0; v < VOCAB; ++v) {
        float r = 0.f;
        int p1 = voff[v + 1];
        for (int p = voff[v]; p < p1; ++p) r += wrow[(size_t)vpos[p] * KCONV];
        arow[v * KCONV] = r;
    }
}

__global__ __launch_bounds__(128) void k_conv(const float* __restrict__ Am,
                                              const float* __restrict__ Bm,
                                              const float* __restrict__ convb,
                                              float* __restrict__ out) {
    __shared__ float As[AROW];
    const int g = blockIdx.x, tid = threadIdx.x;
    for (int i = tid; i < AROW; i += 128) As[i] = Am[(size_t)g * AROW + i];
    __syncthreads();
    if (tid >= CONVO) return;
    const int p = tid;
    float acc[NFILT] = {};
    for (int vk = 0; vk < VK; ++vk) {
        float b = Bm[vk * CONVO + p];
#pragma unroll
        for (int o = 0; o < NFILT; ++o) acc[o] += As[o * VK + vk] * b;
    }
#pragma unroll
    for (int o = 0; o < NFILT; ++o)
        out[(size_t)g * (NFILT * CONVO) + o * CONVO + p] = acc[o] + convb[o];
}

// ---------------------------------------------------------------- launch
extern "C" void kernel_launch(void* const* d_in, const int* in_sizes, int n_in,
                              void* d_out, int out_size, void* d_ws, size_t ws_size,
                              hipStream_t stream) {
    const float* x        = (const float*)d_in[0];
    const int*   ei       = (const int*)d_in[1];
    const int*   batch    = (const int*)d_in[2];
    const int*   target   = (const int*)d_in[3];
    const float* gat_W    = (const float*)d_in[4];
    const float* gat_as   = (const float*)d_in[5];
    const float* gat_ad   = (const float*)d_in[6];
    const float* gat_b    = (const float*)d_in[7];
    const float* gcn_W    = (const float*)d_in[8];
    const float* gcn_b    = (const float*)d_in[9];
    const float* fcg1_W   = (const float*)d_in[10];
    const float* fcg1_b   = (const float*)d_in[11];
    const float* fcg2_W   = (const float*)d_in[12];
    const float* fcg2_b   = (const float*)d_in[13];
    const float* emb      = (const float*)d_in[14];
    const float* conv_W   = (const float*)d_in[15];
    const float* conv_b   = (const float*)d_in[16];
    const float* fcxt_W   = (const float*)d_in[17];
    const float* fcxt_b   = (const float*)d_in[18];
    const float* fc1_W    = (const float*)d_in[19];
    const float* fc1_b    = (const float*)d_in[20];
    const float* fc2_W    = (const float*)d_in[21];
    const float* fc2_b    = (const float*)d_in[22];
    const float* out_W    = (const float*)d_in[23];
    const float* out_b    = (const float*)d_in[24];
    float* outp = (float*)d_out;

    // ---- workspace layout (float units) ----
    // R1: h -> {yAh,yAl} -> small arena.     R2: x1 -> x2.
    const size_t R1SZ = 19600000, R2SZ = 19600000;
    float* R1   = (float*)d_ws;
    float* R2   = R1 + R1SZ;
    float* xAf  = R2 + R2SZ;                          // 2,000,000 (xAh+xAl)
    float* gWf  = xAf + 2000000;                      // 64,000
    float* cWf  = gWf + 64000;                        // 612,000 (cWh+cWl)
    float* asrc = cWf + 612000;
    float* adst = asrc + (size_t)NN * HEADS;
    float* mbuf = adst + (size_t)NN * HEADS;
    float* dbuf = mbuf + (size_t)NN * HEADS;
    float* dinv = dbuf + (size_t)NN * HEADS;
    int* deg      = (int*)(dinv + NN);
    int* csr_off  = deg + NN;
    int* csr_fill = csr_off + (NN + 1);
    int* csr_src  = csr_fill + NN;
    int* gstart   = csr_src + NEP;

    u16* xAh = (u16*)xAf;             u16* xAl = xAh + (size_t)NN * KP_GAT;
    u16* gWh = (u16*)gWf;             u16* gWl = gWh + (size_t)HF * KP_GAT;
    u16* cWh = (u16*)cWf;             u16* cWl = cWh + (size_t)HF * KP_GCN;

    hipMemsetAsync(deg, 0, NN * sizeof(int), stream);
    hipMemsetAsync(csr_fill, 0, NN * sizeof(int), stream);

    // ---- GAT: h = x @ gat_W via split-bf16 MFMA ----
    k_split<<<(NN * (KP_GAT / 2) + 255) / 256, 256, 0, stream>>>(x, xAh, xAl, NN, FXD, KP_GAT);
    k_tsplit<<<dim3((HF + 31) / 32, (KP_GAT + 31) / 32), 256, 0, stream>>>(
        gat_W, gWh, gWl, FXD, HF, KP_GAT);
    k_tsplit<<<dim3((HF + 31) / 32, (KP_GCN + 31) / 32), 256, 0, stream>>>(
        gcn_W, cWh, cWl, HF, HF, KP_GCN);
    k_mfma_gemm<<<dim3((NN + 127) / 128, (HF + 127) / 128), 256, 0, stream>>>(
        xAh, xAl, gWh, gWl, nullptr, R1, NN, HF, KP_GAT, HF, 0);        // h -> R1

    k_att<<<(NN + 3) / 4, 256, 0, stream>>>(R1, gat_as, gat_ad, asrc, adst);
    k_deg<<<(NEP + 255) / 256, 256, 0, stream>>>(ei, deg);
    k_scan<<<1, 1024, 0, stream>>>(deg, csr_off);
    k_fill<<<(NEP + 255) / 256, 256, 0, stream>>>(ei, csr_off, csr_fill, csr_src);
    k_dinv<<<(NN + 255) / 256, 256, 0, stream>>>(deg, dinv);
    k_mden<<<(NN * HEADS + 255) / 256, 256, 0, stream>>>(csr_off, csr_src, asrc, adst, mbuf, dbuf);
    k_gat_feat<<<NN, 256, 0, stream>>>(csr_off, csr_src, asrc, adst, mbuf, dbuf,
                                       R1, gat_b, R2);                  // x1 -> R2 (h in R1 dead)

    // ---- GCN: aggregate + inline bf16-split (x1 in R2 -> yA in R1), then MFMA ----
    k_gcn_agg<<<NN, 256, 0, stream>>>(csr_off, csr_src, dinv, R2, (u16*)R1,
                                      (u16*)R1 + (size_t)NN * KP_GCN);
    k_mfma_gemm<<<dim3((NN + 127) / 128, (HF + 127) / 128), 256, 0, stream>>>(
        (u16*)R1, (u16*)R1 + (size_t)NN * KP_GCN, cWh, cWl, gcn_b, R2,
        NN, HF, KP_GCN, HF, 1);                                         // x2 -> R2 (x1 dead)

    // ---- pooling + graph MLP (arena in R1; yA dead after GCN GEMM) ----
    float* poolR = R1;
    float* xg1R  = poolR + (size_t)NG * 2 * HF;
    float* xcR   = xg1R + (size_t)NG * 1024;
    float* f1R   = xcR + (size_t)NG * 256;
    float* f2R   = f1R + (size_t)NG * 1024;
    float* AmatR = f2R + (size_t)NG * 512;
    float* BmatR = AmatR + (size_t)NG * AROW;
    float* convR = BmatR + (size_t)VK * CONVO;
    float* partR = convR + (size_t)NG * NFILT * CONVO;

    k_gstart<<<1, 1024, 0, stream>>>(batch, gstart);
    k_pool<<<NG, 256, 0, stream>>>(gstart, R2, poolR);
    k_gemm_sk<<<dim3(8, 16, 8), 256, 0, stream>>>(poolR, fcg1_W, partR, NG, 1024, 1560, 208);
    k_reduce<<<512, 256, 0, stream>>>(partR, fcg1_b, xg1R, NG, 1024, 8, 1024, 1);
    k_gemm_sk<<<dim3(8, 2, 16), 256, 0, stream>>>(xg1R, fcg2_W, partR, NG, 128, 1024, 64);
    k_reduce<<<64, 256, 0, stream>>>(partR, fcg2_b, xcR, NG, 128, 16, 256, 0);

    // ---- target CNN branch (vocab-factorized conv) ----
    k_bmat<<<VK, 128, 0, stream>>>(emb, BmatR);
    k_Amat<<<NG, 256, 0, stream>>>(target, conv_W, AmatR);
    k_conv<<<NG, 128, 0, stream>>>(AmatR, BmatR, conv_b, convR);
    k_gemm_sk<<<dim3(8, 2, 16), 256, 0, stream>>>(convR, fcxt_W, partR, NG, 128, 3872, 256);
    k_reduce<<<64, 256, 0, stream>>>(partR, fcxt_b, xcR + 128, NG, 128, 16, 256, 0);

    // ---- fusion head ----
    k_gemm_sk<<<dim3(8, 16, 4), 256, 0, stream>>>(xcR, fc1_W, partR, NG, 1024, 256, 64);
    k_reduce<<<512, 256, 0, stream>>>(partR, fc1_b, f1R, NG, 1024, 4, 1024, 1);
    k_gemm_sk<<<dim3(8, 8, 8), 256, 0, stream>>>(f1R, fc2_W, partR, NG, 512, 1024, 128);
    k_reduce<<<256, 256, 0, stream>>>(partR, fc2_b, f2R, NG, 512, 8, 512, 1);
    k_gemv_out<<<128, 256, 0, stream>>>(f2R, out_W, out_b, outp);
}